// Round 7
// baseline (4440.673 us; speedup 1.0000x reference)
//
#include <hip/hip_runtime.h>

typedef unsigned short u16;
typedef unsigned int u32;

#define NT 262144      // B*T global tokens
#define B_SZ 512
#define T_LEN 512
#define NQv 1000

__device__ __forceinline__ float sigm(float x) { return 1.0f / (1.0f + __expf(-x)); }
__device__ __forceinline__ float tanh_fast(float x) {
    float e2 = __expf(2.0f * x);
    return 1.0f - 2.0f / (e2 + 1.0f);   // safe at +inf
}

// ---------------- kernel 1: per-chunk-token softmax attention w [ctok][50] (fp32) ----------------
__global__ __launch_bounds__(256) void k_w(const int* __restrict__ q_data,
                                           const float* __restrict__ qeW,
                                           const float* __restrict__ Mk,
                                           float* __restrict__ w_out,
                                           int t0, int tcl2) {
    __shared__ float mk[3200];       // Mk fp32 [50][64]
    int tid = threadIdx.x;
    for (int i = tid; i < 3200; i += 256) mk[i] = Mk[i];

    int ctok = blockIdx.x * 256 + tid;
    int b = ctok >> tcl2;
    int tc = ctok & ((1 << tcl2) - 1);
    int gtok = (b << 9) + t0 + tc;
    int q = q_data[gtok];

    const float* qp = qeW + (size_t)q * 64;
    __syncthreads();

    float lg[50];
#pragma unroll
    for (int m = 0; m < 50; m++) {
        const float* mr = &mk[m * 64];
        float acc = 0.f;
#pragma unroll
        for (int k = 0; k < 64; k++) acc = fmaf(qp[k], mr[k], acc);
        lg[m] = acc;
    }
    float mx = -1e30f;
#pragma unroll
    for (int m = 0; m < 50; m++) mx = fmaxf(mx, lg[m]);
    float sum = 0.f;
#pragma unroll
    for (int m = 0; m < 50; m++) { lg[m] = __expf(lg[m] - mx); sum += lg[m]; }
    float inv = 1.0f / sum;
    float* wp = w_out + (size_t)ctok * 50;
#pragma unroll
    for (int m = 0; m < 50; m++) wp[m] = lg[m] * inv;
}

// ---------------- kernel 2 (SCALAR): e/a = act(ve @ W + b), LDS-tiled, fp32 ----------------
__global__ __launch_bounds__(256) void k_ea_scalar(const int* __restrict__ q_data,
                                                   const int* __restrict__ r_data,
                                                   const float* __restrict__ vW,
                                                   const float* __restrict__ vb,
                                                   const float* __restrict__ eW,
                                                   const float* __restrict__ eb,
                                                   const float* __restrict__ aW,
                                                   const float* __restrict__ ab,
                                                   float* __restrict__ e_out,
                                                   float* __restrict__ a_out,
                                                   int t0, int tcl2) {
    __shared__ float sW[64 * 256];   // W[k0+kk][n]
    __shared__ float sve[32 * 64];   // ve[t][kk]
    __shared__ int s_idx[32];
    __shared__ float s_rs[32];
    __shared__ float s_valf[32];

    int tid = threadIdx.x;
    int tok0 = blockIdx.x * 32;          // ctok base
    int is_add = blockIdx.y;
    const float* W = is_add ? aW : eW;
    const float* bias = is_add ? ab : eb;
    float* outp = is_add ? a_out : e_out;

    if (tid < 32) {
        int ctok = tok0 + tid;
        int b = ctok >> tcl2;
        int tc = ctok & ((1 << tcl2) - 1);
        int gtok = (b << 9) + t0 + tc;
        int q = q_data[gtok];
        s_idx[tid] = (q > 0) ? (q - 1) : 0;
        s_rs[tid] = (float)r_data[gtok] * 0.25f;
        s_valf[tid] = (q > 0) ? 1.0f : 0.0f;
    }

    float acc[32];
#pragma unroll
    for (int t = 0; t < 32; t++) acc[t] = 0.f;

    for (int k0 = 0; k0 < 256; k0 += 64) {
        __syncthreads();
        for (int i = tid; i < 16384; i += 256) {
            int kk = i >> 8, nn = i & 255;
            sW[i] = W[(size_t)(k0 + kk) * 256 + nn];
        }
        for (int i = tid; i < 2048; i += 256) {
            int t = i >> 6, kk = i & 63;
            int k = k0 + kk;
            float v = s_valf[t] * fmaf(s_rs[t], vW[(size_t)(NQv + s_idx[t]) * 256 + k],
                                       vW[(size_t)s_idx[t] * 256 + k]);
            sve[i] = v + vb[k];
        }
        __syncthreads();
        for (int kk = 0; kk < 64; kk++) {
            float wv = sW[kk * 256 + tid];
#pragma unroll
            for (int t = 0; t < 32; t++)
                acc[t] = fmaf(sve[t * 64 + kk], wv, acc[t]);
        }
    }

    float bv = bias[tid];
#pragma unroll
    for (int t = 0; t < 32; t++) {
        float x = acc[t] + bv;
        float y = is_add ? tanh_fast(x) : sigm(x);
        outp[(size_t)(tok0 + t) * 256 + tid] = y;
    }
}

// ---------------- kernel 3: sequential scan over chunk, one block per batch (fp32) ----------------
__global__ __launch_bounds__(256) void k_scan(const float* __restrict__ w_buf,
                                              const float* e_buf,
                                              const float* __restrict__ a_buf,
                                              const float* __restrict__ Mv0,
                                              float* __restrict__ Mv_state,
                                              float* reads_out,
                                              int Tc, int first, int store) {
    int b = blockIdx.x;
    int tid = threadIdx.x;       // column v of Mv [50][256]
    __shared__ float wls[52];

    float Mv[50];
    if (first) {
#pragma unroll
        for (int m = 0; m < 50; m++) Mv[m] = Mv0[m * 256 + tid];
    } else {
#pragma unroll
        for (int m = 0; m < 50; m++) Mv[m] = Mv_state[((size_t)b * 50 + m) * 256 + tid];
    }

    size_t base = (size_t)b * Tc;
    for (int t = 0; t < Tc; t++) {
        __syncthreads();
        if (tid < 50) wls[tid] = w_buf[(base + t) * 50 + tid];
        __syncthreads();
        float e = e_buf[(base + t) * 256 + tid];
        float a = a_buf[(base + t) * 256 + tid];
        float rd = 0.f;
#pragma unroll
        for (int m = 0; m < 50; m++) {
            float wm = wls[m];
            rd = fmaf(wm, Mv[m], rd);                 // read BEFORE write
            float tmp = fmaf(-e, Mv[m], a);           // a - e*Mv
            Mv[m] = fmaf(wm, tmp, Mv[m]);             // Mv + w*(a - e*Mv)
        }
        reads_out[(base + t) * 256 + tid] = rd;       // overwrites e_buf[t] (consumed)
    }
    if (store) {
#pragma unroll
        for (int m = 0; m < 50; m++) Mv_state[((size_t)b * 50 + m) * 256 + tid] = Mv[m];
    }
}

// ---------------- kernel 4a (SCALAR): summary = tanh([reads|qe] @ sW + sb), fp32 ----------------
__global__ __launch_bounds__(256) void k_sum_scalar(const float* __restrict__ reads,
                                                    const int* __restrict__ q_data,
                                                    const float* __restrict__ qeW,
                                                    const float* __restrict__ sW,
                                                    const float* __restrict__ sb,
                                                    float* __restrict__ S_out,
                                                    int t0, int tcl2) {
    int id = blockIdx.x * 256 + threadIdx.x;    // id = ctok*50 + n
    int ctok = id / 50;
    int n = id - ctok * 50;
    int b = ctok >> tcl2;
    int tc = ctok & ((1 << tcl2) - 1);
    int gtok = (b << 9) + t0 + tc;

    const float* rp = reads + (size_t)ctok * 256;
    const float* wp = sW + n;                   // sW[k*50 + n]
    float acc = sb[n];
#pragma unroll 8
    for (int k = 0; k < 256; k++) acc = fmaf(rp[k], wp[(size_t)k * 50], acc);
    const float* qp = qeW + (size_t)q_data[gtok] * 64;
#pragma unroll 8
    for (int k = 0; k < 64; k++) acc = fmaf(qp[k], wp[(size_t)(256 + k) * 50], acc);
    S_out[id] = tanh_fast(acc);
}

// ---------------- kernel 4b: per-token heads (outputs FP32) ----------------
__global__ __launch_bounds__(256) void k_heads(const float* __restrict__ S,
                                               const int* __restrict__ q_data,
                                               const float* __restrict__ qeW,
                                               const float* __restrict__ abilW,
                                               const float* __restrict__ abilb,
                                               const float* __restrict__ tW,
                                               const float* __restrict__ tb,
                                               const float* __restrict__ dW,
                                               const float* __restrict__ db,
                                               const float* __restrict__ cW,
                                               const float* __restrict__ cb,
                                               float* __restrict__ out,
                                               int t0, int tcl2) {
    int tid = threadIdx.x;
    int ctok = blockIdx.x * 256 + tid;
    int b = ctok >> tcl2;
    int tc = ctok & ((1 << tcl2) - 1);
    int gtok = (b << 9) + t0 + tc;

    float s[50], qe[64];
    {
        const float* sr = S + (size_t)ctok * 50;
#pragma unroll
        for (int i = 0; i < 50; i++) s[i] = sr[i];
        int q = q_data[gtok];
        const float4* qr = (const float4*)(qeW + (size_t)q * 64);
#pragma unroll
        for (int i = 0; i < 16; i++) {
            float4 u = qr[i];
            qe[4 * i + 0] = u.x; qe[4 * i + 1] = u.y;
            qe[4 * i + 2] = u.z; qe[4 * i + 3] = u.w;
        }
    }
    float th = abilb[0];
#pragma unroll
    for (int j = 0; j < 50; j++) th = fmaf(s[j], abilW[j], th);
    out[gtok] = th * 3.0f;

    float bt0 = tb[0], bt1 = tb[1], bt2 = tb[2], bt3 = tb[3];
#pragma unroll
    for (int k = 0; k < 64; k++) {
        float x = qe[k];
        bt0 = fmaf(x, tW[k * 4 + 0], bt0);
        bt1 = fmaf(x, tW[k * 4 + 1], bt1);
        bt2 = fmaf(x, tW[k * 4 + 2], bt2);
        bt3 = fmaf(x, tW[k * 4 + 3], bt3);
    }
    out[NT + (size_t)gtok * 4 + 0] = bt0;
    out[NT + (size_t)gtok * 4 + 1] = bt1;
    out[NT + (size_t)gtok * 4 + 2] = bt2;
    out[NT + (size_t)gtok * 4 + 3] = bt3;

    float da = db[0];
    float l0 = cb[0], l1 = cb[1], l2 = cb[2], l3 = cb[3];
#pragma unroll
    for (int i = 0; i < 50; i++) {
        float x = s[i];
        da = fmaf(x, dW[i], da);
        l0 = fmaf(x, cW[i * 4 + 0], l0);
        l1 = fmaf(x, cW[i * 4 + 1], l1);
        l2 = fmaf(x, cW[i * 4 + 2], l2);
        l3 = fmaf(x, cW[i * 4 + 3], l3);
    }
#pragma unroll
    for (int k = 0; k < 64; k++) {
        float x = qe[k];
        int i = 50 + k;
        da = fmaf(x, dW[i], da);
        l0 = fmaf(x, cW[i * 4 + 0], l0);
        l1 = fmaf(x, cW[i * 4 + 1], l1);
        l2 = fmaf(x, cW[i * 4 + 2], l2);
        l3 = fmaf(x, cW[i * 4 + 3], l3);
    }
    float alpha = logf(1.0f + __expf(da));
    out[5 * (size_t)NT + gtok] = alpha;

    out[11 * (size_t)NT + (size_t)gtok * 4 + 0] = l0;
    out[11 * (size_t)NT + (size_t)gtok * 4 + 1] = l1;
    out[11 * (size_t)NT + (size_t)gtok * 4 + 2] = l2;
    out[11 * (size_t)NT + (size_t)gtok * 4 + 3] = l3;

    float c0 = sigm(l0);
    float c1 = c0 * sigm(l1);
    float c2 = c1 * sigm(l2);
    float c3 = c2 * sigm(l3);
    size_t pb = 6 * (size_t)NT + (size_t)gtok * 5;
    out[pb + 0] = 1.0f - c0;
    out[pb + 1] = c0 - c1;
    out[pb + 2] = c1 - c2;
    out[pb + 3] = c2 - c3;
    out[pb + 4] = c3;
}

extern "C" void kernel_launch(void* const* d_in, const int* in_sizes, int n_in,
                              void* d_out, int out_size, void* d_ws, size_t ws_size,
                              hipStream_t stream) {
    (void)in_sizes; (void)n_in; (void)out_size;
    const int* q_data = (const int*)d_in[0];
    const int* r_data = (const int*)d_in[1];
    const float* qeW = (const float*)d_in[2];
    const float* Mk  = (const float*)d_in[3];
    const float* Mv0 = (const float*)d_in[4];
    const float* vW  = (const float*)d_in[5];
    const float* vb  = (const float*)d_in[6];
    const float* eW  = (const float*)d_in[7];
    const float* eb  = (const float*)d_in[8];
    const float* aW  = (const float*)d_in[9];
    const float* ab  = (const float*)d_in[10];
    const float* sW  = (const float*)d_in[11];
    const float* sb  = (const float*)d_in[12];
    const float* abilW = (const float*)d_in[13];
    const float* abilb = (const float*)d_in[14];
    const float* tW  = (const float*)d_in[15];
    const float* tb  = (const float*)d_in[16];
    const float* dW  = (const float*)d_in[17];
    const float* db  = (const float*)d_in[18];
    const float* cW  = (const float*)d_in[19];
    const float* cb  = (const float*)d_in[20];

    // fp32 workspace. footprint(Tc) = 26,214,400 + 1,150,976*Tc bytes
    int Tc = 8;
    const int cands[7] = {512, 256, 128, 64, 32, 16, 8};
    for (int i = 0; i < 7; i++) {
        size_t need = 26214400ULL + 1150976ULL * (size_t)cands[i];
        if (need <= ws_size) { Tc = cands[i]; break; }
    }
    int tcl2 = 31 - __builtin_clz((u32)Tc);
    int nch = T_LEN / Tc;

    char* ws = (char*)d_ws;
    float* MvSt = (float*)(ws + 0);                             // 26,214,400 B
    float* w_c  = (float*)(ws + 26214400);                      // 102,400*Tc B (alias S)
    float* e_c  = (float*)(ws + 26214400 + 102400ULL * Tc);     // 524,288*Tc B (alias reads)
    float* a_c  = (float*)(ws + 26214400 + 626688ULL * Tc);     // 524,288*Tc B
    float* S_c  = w_c;
    float* reads = e_c;
    float* out  = (float*)d_out;

    int rows = B_SZ * Tc;

    for (int c = 0; c < nch; c++) {
        int t0 = c * Tc;
        k_w<<<rows / 256, 256, 0, stream>>>(q_data, qeW, Mk, w_c, t0, tcl2);
        dim3 g2(rows / 32, 2);
        k_ea_scalar<<<g2, 256, 0, stream>>>(q_data, r_data, vW, vb, eW, eb, aW, ab,
                                            e_c, a_c, t0, tcl2);
        k_scan<<<B_SZ, 256, 0, stream>>>(w_c, e_c, a_c, Mv0, MvSt, reads, Tc,
                                         (c == 0) ? 1 : 0, (c < nch - 1) ? 1 : 0);
        k_sum_scalar<<<(rows / 256) * 50, 256, 0, stream>>>(reads, q_data, qeW, sW, sb,
                                                            S_c, t0, tcl2);
        k_heads<<<rows / 256, 256, 0, stream>>>(S_c, q_data, qeW, abilW, abilb, tW, tb,
                                                dW, db, cW, cb, out, t0, tcl2);
    }
}

// Round 8
// 1148.947 us; speedup vs baseline: 3.8650x; 3.8650x over previous
//
#include <hip/hip_runtime.h>

typedef unsigned short u16;
typedef unsigned int u32;
typedef __bf16 bf16x8 __attribute__((ext_vector_type(8)));
typedef float fx4 __attribute__((ext_vector_type(4)));

#define NT 262144      // B*T global tokens
#define B_SZ 512
#define T_LEN 512
#define NQv 1000

__device__ __forceinline__ float bf2f(u16 u) { return __uint_as_float(((u32)u) << 16); }
__device__ __forceinline__ float bflo(u32 u) { return __uint_as_float(u << 16); }
__device__ __forceinline__ float bfhi(u32 u) { return __uint_as_float(u & 0xffff0000u); }
__device__ __forceinline__ u16 f2bf(float f) {
    u32 x = __float_as_uint(f);
    x += 0x7fffu + ((x >> 16) & 1u);
    return (u16)(x >> 16);
}
__device__ __forceinline__ u32 pack2(float a, float b) {
    return (u32)f2bf(a) | ((u32)f2bf(b) << 16);
}
__device__ __forceinline__ float sigm(float x) { return 1.0f / (1.0f + __expf(-x)); }
__device__ __forceinline__ float tanh_fast(float x) {
    float e2 = __expf(2.0f * x);
    return 1.0f - 2.0f / (e2 + 1.0f);   // safe at +inf
}

// ---------------- kernel 0: transpose fp32 weights -> k-contiguous bf16 B layouts ----------------
__global__ __launch_bounds__(256) void k_prep_w(const float* __restrict__ eW,
                                                const float* __restrict__ aW,
                                                const float* __restrict__ sW,
                                                u16* __restrict__ Wt,
                                                u16* __restrict__ SWt) {
    int id = blockIdx.x * 256 + threadIdx.x;
    if (id < 131072) {
        int n = id >> 8, k = id & 255;
        Wt[n * 256 + k] = f2bf((n < 256) ? eW[k * 256 + n] : aW[k * 256 + (n - 256)]);
    } else {
        int id2 = id - 131072;
        if (id2 < 64 * 320) {
            int n = id2 / 320, k = id2 - n * 320;
            SWt[n * 320 + k] = (n < 50) ? f2bf(sW[k * 50 + n]) : (u16)0;
        }
    }
}

// ---------------- kernel 1: per-chunk-token softmax attention w [ctok][50] (bf16 out) ----------------
__global__ __launch_bounds__(256) void k_w(const int* __restrict__ q_data,
                                           const float* __restrict__ qeW,
                                           const float* __restrict__ Mk,
                                           u16* __restrict__ w_out,
                                           int t0, int tcl2) {
    __shared__ __align__(16) float mk[3200];       // Mk fp32 [50][64]
    __shared__ __align__(16) u16 wtile[256 * 50];
    int tid = threadIdx.x;
    for (int i = tid; i < 3200; i += 256) mk[i] = Mk[i];

    int ctok = blockIdx.x * 256 + tid;
    int b = ctok >> tcl2;
    int tc = ctok & ((1 << tcl2) - 1);
    int gtok = (b << 9) + t0 + tc;
    int q = q_data[gtok];

    float qe[64];
    {
        const float4* qr = (const float4*)(qeW + (size_t)q * 64);
#pragma unroll
        for (int i = 0; i < 16; i++) {
            float4 u = qr[i];
            qe[4 * i + 0] = u.x; qe[4 * i + 1] = u.y;
            qe[4 * i + 2] = u.z; qe[4 * i + 3] = u.w;
        }
    }
    __syncthreads();

    float lg[50];
#pragma unroll
    for (int m = 0; m < 50; m++) {
        const float* mr = &mk[m * 64];
        float acc = 0.f;
#pragma unroll
        for (int k = 0; k < 64; k++) acc = fmaf(qe[k], mr[k], acc);
        lg[m] = acc;
    }
    float mx = -1e30f;
#pragma unroll
    for (int m = 0; m < 50; m++) mx = fmaxf(mx, lg[m]);
    float sum = 0.f;
#pragma unroll
    for (int m = 0; m < 50; m++) { lg[m] = __expf(lg[m] - mx); sum += lg[m]; }
    float inv = 1.0f / sum;
#pragma unroll
    for (int m = 0; m < 50; m++) wtile[tid * 50 + m] = f2bf(lg[m] * inv);

    __syncthreads();

    int wave = tid >> 6, lane = tid & 63;
    int wave_ctok0 = blockIdx.x * 256 + wave * 64;
    const uint4* src = (const uint4*)(wtile + wave * 3200);
    uint4* dst = (uint4*)(w_out + (size_t)wave_ctok0 * 50);
    for (int c = lane; c < 400; c += 64) dst[c] = src[c];
}

// ---------------- kernel 2: fused ve-gather + erase/add MFMA GEMM + activations (bf16 out) ----------------
__global__ __launch_bounds__(256) void k_gemm_ea(const int* __restrict__ q_data,
                                                 const int* __restrict__ r_data,
                                                 const float* __restrict__ vW,
                                                 const float* __restrict__ vb,
                                                 const u16* __restrict__ Wt,
                                                 const float* __restrict__ eb,
                                                 const float* __restrict__ ab,
                                                 u16* __restrict__ e_out,
                                                 u16* __restrict__ a_out,
                                                 int t0, int tcl2) {
    __shared__ __align__(16) u16 lA[128 * 32];
    __shared__ __align__(16) u16 lB[128 * 32];
    __shared__ int s_idx[128];
    __shared__ float s_rs[128];
    __shared__ float s_valf[128];
    __shared__ float s_vb[256];

    int tid = threadIdx.x;
    int row0 = blockIdx.x * 128;   // ctok space
    int col0 = blockIdx.y * 128;

    if (tid < 128) {
        int ctok = row0 + tid;
        int b = ctok >> tcl2;
        int tc = ctok & ((1 << tcl2) - 1);
        int gtok = (b << 9) + t0 + tc;
        int q = q_data[gtok];
        s_idx[tid] = (q > 0) ? (q - 1) : 0;
        s_rs[tid] = (float)r_data[gtok] * 0.25f;
        s_valf[tid] = (q > 0) ? 1.0f : 0.0f;
    }
    s_vb[tid] = vb[tid];

    int wave = tid >> 6, lane = tid & 63;
    int wm = wave >> 1, wn = wave & 1;
    int rl = lane & 15, quad = lane >> 4;
    fx4 acc[4][4] = {};
    __syncthreads();

    for (int k0 = 0; k0 < 256; k0 += 32) {
#pragma unroll
        for (int h = 0; h < 2; h++) {
            int c = tid + h * 256;
            int row = c >> 2, j = c & 3;
            const float* pa = vW + (size_t)s_idx[row] * 256 + k0 + j * 8;
            const float* pb = pa + NQv * 256;
            float4 a0 = ((const float4*)pa)[0];
            float4 a1 = ((const float4*)pa)[1];
            float4 b0 = ((const float4*)pb)[0];
            float4 b1 = ((const float4*)pb)[1];
            float vf = s_valf[row], rs = s_rs[row];
            const float* vbp = &s_vb[k0 + j * 8];
            float o0 = vf * fmaf(rs, b0.x, a0.x) + vbp[0];
            float o1 = vf * fmaf(rs, b0.y, a0.y) + vbp[1];
            float o2 = vf * fmaf(rs, b0.z, a0.z) + vbp[2];
            float o3 = vf * fmaf(rs, b0.w, a0.w) + vbp[3];
            float o4 = vf * fmaf(rs, b1.x, a1.x) + vbp[4];
            float o5 = vf * fmaf(rs, b1.y, a1.y) + vbp[5];
            float o6 = vf * fmaf(rs, b1.z, a1.z) + vbp[6];
            float o7 = vf * fmaf(rs, b1.w, a1.w) + vbp[7];
            uint4 o;
            o.x = pack2(o0, o1); o.y = pack2(o2, o3);
            o.z = pack2(o4, o5); o.w = pack2(o6, o7);
            *(uint4*)(lA + (size_t)c * 8) = o;
        }
#pragma unroll
        for (int h = 0; h < 2; h++) {
            int c = tid + h * 256;
            int n = c >> 2, j = c & 3;
            uint4 u = *(const uint4*)(Wt + (size_t)(col0 + n) * 256 + k0 + j * 8);
            *(uint4*)(lB + (size_t)c * 8) = u;
        }
        __syncthreads();
        bf16x8 af[4], bfr[4];
#pragma unroll
        for (int i = 0; i < 4; i++) af[i] = *(const bf16x8*)(lA + (wm * 64 + i * 16 + rl) * 32 + quad * 8);
#pragma unroll
        for (int j = 0; j < 4; j++) bfr[j] = *(const bf16x8*)(lB + (wn * 64 + j * 16 + rl) * 32 + quad * 8);
#pragma unroll
        for (int i = 0; i < 4; i++)
#pragma unroll
            for (int j = 0; j < 4; j++)
                acc[i][j] = __builtin_amdgcn_mfma_f32_16x16x32_bf16(af[i], bfr[j], acc[i][j], 0, 0, 0);
        __syncthreads();
    }

    bool is_er = (col0 < 256);
    const float* bias = is_er ? eb : ab;
    u16* outp = is_er ? e_out : a_out;
    int cb0 = is_er ? col0 : (col0 - 256);
#pragma unroll
    for (int j = 0; j < 4; j++) {
        int n = cb0 + wn * 64 + j * 16 + rl;
        float bv = bias[n];
#pragma unroll
        for (int i = 0; i < 4; i++) {
            int rowb = row0 + wm * 64 + i * 16 + quad * 4;
#pragma unroll
            for (int r = 0; r < 4; r++) {
                float x = acc[i][j][r] + bv;
                float y = is_er ? sigm(x) : tanh_fast(x);
                outp[(size_t)(rowb + r) * 256 + n] = f2bf(y);
            }
        }
    }
}

// ---------------- kernel 3: sequential scan, one block per batch (bf16 buffers, fp32 regs) ----------------
// e_buf and reads_out alias on purpose.
__global__ __launch_bounds__(256) void k_scan(const u16* __restrict__ w_buf,
                                              const u16* e_buf,
                                              const u16* __restrict__ a_buf,
                                              const float* __restrict__ Mv0,
                                              u16* __restrict__ Mv_state,
                                              u16* reads_out,
                                              int Tc, int first, int store) {
    int b = blockIdx.x;
    int tid = threadIdx.x;
    __shared__ __align__(16) float wls[2][52];

    float Mv[50];
    if (first) {
#pragma unroll
        for (int m = 0; m < 50; m++) Mv[m] = Mv0[m * 256 + tid];
    } else {
#pragma unroll
        for (int m = 0; m < 50; m++) Mv[m] = bf2f(Mv_state[((size_t)b * 50 + m) * 256 + tid]);
    }

    size_t base = (size_t)b * Tc;
    if (tid < 25) {
        u32 u = ((const u32*)(w_buf + base * 50))[tid];
        wls[0][2 * tid] = bflo(u);
        wls[0][2 * tid + 1] = bfhi(u);
    }
    u16 eu = e_buf[base * 256 + tid];
    u16 au = a_buf[base * 256 + tid];
    __syncthreads();

    for (int t = 0; t < Tc; t++) {
        float e = bf2f(eu), a = bf2f(au);
        int tn = (t + 1 < Tc) ? (t + 1) : (Tc - 1);
        u16 eu_n = e_buf[(base + tn) * 256 + tid];
        u16 au_n = a_buf[(base + tn) * 256 + tid];
        if (tid < 25) {
            u32 u = ((const u32*)(w_buf + (base + tn) * 50))[tid];
            wls[(t + 1) & 1][2 * tid] = bflo(u);
            wls[(t + 1) & 1][2 * tid + 1] = bfhi(u);
        }
        const float* wv = wls[t & 1];
        float rd = 0.f;
#pragma unroll
        for (int m = 0; m < 50; m++) {
            float wm = wv[m];
            rd = fmaf(wm, Mv[m], rd);                 // read BEFORE write
            float tmp = fmaf(-e, Mv[m], a);           // a - e*Mv
            Mv[m] = fmaf(wm, tmp, Mv[m]);             // Mv + w*(a - e*Mv)
        }
        reads_out[(base + t) * 256 + tid] = f2bf(rd); // overwrites e_buf[t] (consumed)
        eu = eu_n; au = au_n;
        __syncthreads();
    }
    if (store) {
#pragma unroll
        for (int m = 0; m < 50; m++) Mv_state[((size_t)b * 50 + m) * 256 + tid] = f2bf(Mv[m]);
    }
}

// ---------------- kernel 4: fused summary MFMA + heads (fp32 out) ----------------
__global__ __launch_bounds__(256) void k_sum_heads(const u16* __restrict__ reads,
                                                   const int* __restrict__ q_data,
                                                   const float* __restrict__ qeW,
                                                   const u16* __restrict__ SWt,
                                                   const float* __restrict__ sb,
                                                   const float* __restrict__ abilW,
                                                   const float* __restrict__ abilb,
                                                   const float* __restrict__ tW,
                                                   const float* __restrict__ tb,
                                                   const float* __restrict__ dW,
                                                   const float* __restrict__ db,
                                                   const float* __restrict__ cW,
                                                   const float* __restrict__ cb,
                                                   float* __restrict__ out,
                                                   int t0, int tcl2) {
    __shared__ __align__(16) u16 lA[128 * 32];
    __shared__ __align__(16) u16 lB[64 * 32];
    __shared__ float sS[128 * 52];
    __shared__ int s_q[128];
    int tid = threadIdx.x;
    int row0 = blockIdx.x * 128;
    if (tid < 128) {
        int ctok = row0 + tid;
        int b = ctok >> tcl2;
        int tc = ctok & ((1 << tcl2) - 1);
        s_q[tid] = q_data[(b << 9) + t0 + tc];
    }
    int wave = tid >> 6, lane = tid & 63;
    int wm = wave >> 1, wn = wave & 1;
    int rl = lane & 15, quad = lane >> 4;
    fx4 acc[4][2] = {};
    __syncthreads();

    for (int ks = 0; ks < 10; ks++) {
        int k0 = ks * 32;
#pragma unroll
        for (int h = 0; h < 2; h++) {
            int c = tid + h * 256;
            int row = c >> 2, j = c & 3;
            if (k0 < 256) {
                uint4 u = *(const uint4*)(reads + (size_t)(row0 + row) * 256 + k0 + j * 8);
                *(uint4*)(lA + (size_t)c * 8) = u;
            } else {
                const float* src = qeW + (size_t)s_q[row] * 64 + (k0 - 256) + j * 8;
                float4 f0 = ((const float4*)src)[0];
                float4 f1 = ((const float4*)src)[1];
                uint4 o;
                o.x = pack2(f0.x, f0.y); o.y = pack2(f0.z, f0.w);
                o.z = pack2(f1.x, f1.y); o.w = pack2(f1.z, f1.w);
                *(uint4*)(lA + (size_t)c * 8) = o;
            }
        }
        {
            int c = tid, n = c >> 2, j = c & 3;
            uint4 u = *(const uint4*)(SWt + (size_t)n * 320 + k0 + j * 8);
            *(uint4*)(lB + (size_t)c * 8) = u;
        }
        __syncthreads();
        bf16x8 af[4], bfr[2];
#pragma unroll
        for (int i = 0; i < 4; i++) af[i] = *(const bf16x8*)(lA + (wm * 64 + i * 16 + rl) * 32 + quad * 8);
#pragma unroll
        for (int j = 0; j < 2; j++) bfr[j] = *(const bf16x8*)(lB + (wn * 32 + j * 16 + rl) * 32 + quad * 8);
#pragma unroll
        for (int i = 0; i < 4; i++)
#pragma unroll
            for (int j = 0; j < 2; j++)
                acc[i][j] = __builtin_amdgcn_mfma_f32_16x16x32_bf16(af[i], bfr[j], acc[i][j], 0, 0, 0);
        __syncthreads();
    }

    // epilogue: S tile -> LDS (fp32)
#pragma unroll
    for (int j = 0; j < 2; j++) {
        int n = wn * 32 + j * 16 + rl;
        if (n < 50) {
            float bv = sb[n];
#pragma unroll
            for (int i = 0; i < 4; i++) {
                int rowl = wm * 64 + i * 16 + quad * 4;
#pragma unroll
                for (int r = 0; r < 4; r++)
                    sS[(rowl + r) * 52 + n] = tanh_fast(acc[i][j][r] + bv);
            }
        }
    }
    __syncthreads();

    // heads: one thread per token (threads 0..127)
    if (tid < 128) {
        int ctok = row0 + tid;
        int b = ctok >> tcl2;
        int tc = ctok & ((1 << tcl2) - 1);
        int gtok = (b << 9) + t0 + tc;
        const float* sp = &sS[tid * 52];

        float qe[64];
        const float4* qr = (const float4*)(qeW + (size_t)s_q[tid] * 64);
#pragma unroll
        for (int i = 0; i < 16; i++) {
            float4 u = qr[i];
            qe[4 * i + 0] = u.x; qe[4 * i + 1] = u.y;
            qe[4 * i + 2] = u.z; qe[4 * i + 3] = u.w;
        }
        float th = abilb[0];
#pragma unroll
        for (int j = 0; j < 50; j++) th = fmaf(sp[j], abilW[j], th);
        out[gtok] = th * 3.0f;

        float bt0 = tb[0], bt1 = tb[1], bt2 = tb[2], bt3 = tb[3];
#pragma unroll
        for (int k = 0; k < 64; k++) {
            float x = qe[k];
            bt0 = fmaf(x, tW[k * 4 + 0], bt0);
            bt1 = fmaf(x, tW[k * 4 + 1], bt1);
            bt2 = fmaf(x, tW[k * 4 + 2], bt2);
            bt3 = fmaf(x, tW[k * 4 + 3], bt3);
        }
        out[NT + (size_t)gtok * 4 + 0] = bt0;
        out[NT + (size_t)gtok * 4 + 1] = bt1;
        out[NT + (size_t)gtok * 4 + 2] = bt2;
        out[NT + (size_t)gtok * 4 + 3] = bt3;

        float da = db[0];
        float l0 = cb[0], l1 = cb[1], l2 = cb[2], l3 = cb[3];
#pragma unroll
        for (int i = 0; i < 50; i++) {
            float x = sp[i];
            da = fmaf(x, dW[i], da);
            l0 = fmaf(x, cW[i * 4 + 0], l0);
            l1 = fmaf(x, cW[i * 4 + 1], l1);
            l2 = fmaf(x, cW[i * 4 + 2], l2);
            l3 = fmaf(x, cW[i * 4 + 3], l3);
        }
#pragma unroll
        for (int k = 0; k < 64; k++) {
            float x = qe[k];
            int i = 50 + k;
            da = fmaf(x, dW[i], da);
            l0 = fmaf(x, cW[i * 4 + 0], l0);
            l1 = fmaf(x, cW[i * 4 + 1], l1);
            l2 = fmaf(x, cW[i * 4 + 2], l2);
            l3 = fmaf(x, cW[i * 4 + 3], l3);
        }
        float alpha = logf(1.0f + __expf(da));
        out[5 * (size_t)NT + gtok] = alpha;

        out[11 * (size_t)NT + (size_t)gtok * 4 + 0] = l0;
        out[11 * (size_t)NT + (size_t)gtok * 4 + 1] = l1;
        out[11 * (size_t)NT + (size_t)gtok * 4 + 2] = l2;
        out[11 * (size_t)NT + (size_t)gtok * 4 + 3] = l3;

        float c0 = sigm(l0);
        float c1 = c0 * sigm(l1);
        float c2 = c1 * sigm(l2);
        float c3 = c2 * sigm(l3);
        size_t pb = 6 * (size_t)NT + (size_t)gtok * 5;
        out[pb + 0] = 1.0f - c0;
        out[pb + 1] = c0 - c1;
        out[pb + 2] = c1 - c2;
        out[pb + 3] = c2 - c3;
        out[pb + 4] = c3;
    }
}

extern "C" void kernel_launch(void* const* d_in, const int* in_sizes, int n_in,
                              void* d_out, int out_size, void* d_ws, size_t ws_size,
                              hipStream_t stream) {
    (void)in_sizes; (void)n_in; (void)out_size;
    const int* q_data = (const int*)d_in[0];
    const int* r_data = (const int*)d_in[1];
    const float* qeW = (const float*)d_in[2];
    const float* Mk  = (const float*)d_in[3];
    const float* Mv0 = (const float*)d_in[4];
    const float* vW  = (const float*)d_in[5];
    const float* vb  = (const float*)d_in[6];
    const float* eW  = (const float*)d_in[7];
    const float* eb  = (const float*)d_in[8];
    const float* aW  = (const float*)d_in[9];
    const float* ab  = (const float*)d_in[10];
    const float* sW  = (const float*)d_in[11];
    const float* sb  = (const float*)d_in[12];
    const float* abilW = (const float*)d_in[13];
    const float* abilb = (const float*)d_in[14];
    const float* tW  = (const float*)d_in[15];
    const float* tb  = (const float*)d_in[16];
    const float* dW  = (const float*)d_in[17];
    const float* db  = (const float*)d_in[18];
    const float* cW  = (const float*)d_in[19];
    const float* cb  = (const float*)d_in[20];

    // bf16 workspace. footprint(Tc) = 13,410,304 + 575,488*Tc bytes
    int Tc = 8;
    const int cands[4] = {64, 32, 16, 8};
    for (int i = 0; i < 4; i++) {
        size_t need = 13410304ULL + 575488ULL * (size_t)cands[i];
        if (need <= ws_size) { Tc = cands[i]; break; }
    }
    int tcl2 = 31 - __builtin_clz((u32)Tc);
    int nch = T_LEN / Tc;

    char* ws = (char*)d_ws;
    u16* Wt    = (u16*)(ws + 0);                          // 262,144 B
    u16* SWt   = (u16*)(ws + 262144);                     // 40,960 B
    u16* MvSt  = (u16*)(ws + 303104);                     // 13,107,200 B (bf16 state)
    u16* w_c   = (u16*)(ws + 13410304);                   // 51,200*Tc B
    u16* e_c   = (u16*)(ws + 13410304 + 51200ULL * Tc);   // 262,144*Tc B (alias reads)
    u16* a_c   = (u16*)(ws + 13410304 + 313344ULL * Tc);  // 262,144*Tc B
    u16* reads = e_c;
    float* out = (float*)d_out;

    int rows = B_SZ * Tc;

    k_prep_w<<<592, 256, 0, stream>>>(eW, aW, sW, Wt, SWt);
    for (int c = 0; c < nch; c++) {
        int t0 = c * Tc;
        k_w<<<rows / 256, 256, 0, stream>>>(q_data, qeW, Mk, w_c, t0, tcl2);
        dim3 g2(rows / 128, 4);
        k_gemm_ea<<<g2, 256, 0, stream>>>(q_data, r_data, vW, vb, Wt, eb, ab, e_c, a_c, t0, tcl2);
        k_scan<<<B_SZ, 256, 0, stream>>>(w_c, e_c, a_c, Mv0, MvSt, reads, Tc,
                                         (c == 0) ? 1 : 0, (c < nch - 1) ? 1 : 0);
        k_sum_heads<<<rows / 128, 256, 0, stream>>>(reads, q_data, qeW, SWt, sb,
                                                    abilW, abilb, tW, tb, dW, db, cW, cb,
                                                    out, t0, tcl2);
    }
}

// Round 9
// 1032.250 us; speedup vs baseline: 4.3019x; 1.1131x over previous
//
#include <hip/hip_runtime.h>

typedef unsigned short u16;
typedef unsigned int u32;
typedef __bf16 bf16x8 __attribute__((ext_vector_type(8)));
typedef float fx4 __attribute__((ext_vector_type(4)));

#define NT 262144      // B*T global tokens
#define B_SZ 512
#define T_LEN 512
#define NQv 1000

__device__ __forceinline__ float bf2f(u16 u) { return __uint_as_float(((u32)u) << 16); }
__device__ __forceinline__ float bflo(u32 u) { return __uint_as_float(u << 16); }
__device__ __forceinline__ float bfhi(u32 u) { return __uint_as_float(u & 0xffff0000u); }
__device__ __forceinline__ u16 f2bf(float f) {
    u32 x = __float_as_uint(f);
    x += 0x7fffu + ((x >> 16) & 1u);
    return (u16)(x >> 16);
}
__device__ __forceinline__ u32 pack2(float a, float b) {
    return (u32)f2bf(a) | ((u32)f2bf(b) << 16);
}
__device__ __forceinline__ float sigm(float x) { return 1.0f / (1.0f + __expf(-x)); }
__device__ __forceinline__ float tanh_fast(float x) {
    float e2 = __expf(2.0f * x);
    return 1.0f - 2.0f / (e2 + 1.0f);   // safe at +inf
}

// ---------------- kernel 0: transpose fp32 weights -> k-contiguous bf16 B layouts ----------------
__global__ __launch_bounds__(256) void k_prep_w(const float* __restrict__ eW,
                                                const float* __restrict__ aW,
                                                const float* __restrict__ sW,
                                                u16* __restrict__ Wt,
                                                u16* __restrict__ SWt) {
    int id = blockIdx.x * 256 + threadIdx.x;
    if (id < 131072) {
        int n = id >> 8, k = id & 255;
        Wt[n * 256 + k] = f2bf((n < 256) ? eW[k * 256 + n] : aW[k * 256 + (n - 256)]);
    } else {
        int id2 = id - 131072;
        if (id2 < 64 * 320) {
            int n = id2 / 320, k = id2 - n * 320;
            SWt[n * 320 + k] = (n < 50) ? f2bf(sW[k * 50 + n]) : (u16)0;
        }
    }
}

// ---------------- kernel 1: per-chunk-token softmax attention w [ctok][50] (bf16 out) ----------------
__global__ __launch_bounds__(256) void k_w(const int* __restrict__ q_data,
                                           const float* __restrict__ qeW,
                                           const float* __restrict__ Mk,
                                           u16* __restrict__ w_out,
                                           int t0, int tcl2) {
    __shared__ __align__(16) float mk[3200];       // Mk fp32 [50][64]
    __shared__ __align__(16) u16 wtile[256 * 50];
    int tid = threadIdx.x;
    for (int i = tid; i < 3200; i += 256) mk[i] = Mk[i];

    int ctok = blockIdx.x * 256 + tid;
    int b = ctok >> tcl2;
    int tc = ctok & ((1 << tcl2) - 1);
    int gtok = (b << 9) + t0 + tc;
    int q = q_data[gtok];

    float qe[64];
    {
        const float4* qr = (const float4*)(qeW + (size_t)q * 64);
#pragma unroll
        for (int i = 0; i < 16; i++) {
            float4 u = qr[i];
            qe[4 * i + 0] = u.x; qe[4 * i + 1] = u.y;
            qe[4 * i + 2] = u.z; qe[4 * i + 3] = u.w;
        }
    }
    __syncthreads();

    float lg[50];
#pragma unroll
    for (int m = 0; m < 50; m++) {
        const float* mr = &mk[m * 64];
        float acc = 0.f;
#pragma unroll
        for (int k = 0; k < 64; k++) acc = fmaf(qe[k], mr[k], acc);
        lg[m] = acc;
    }
    float mx = -1e30f;
#pragma unroll
    for (int m = 0; m < 50; m++) mx = fmaxf(mx, lg[m]);
    float sum = 0.f;
#pragma unroll
    for (int m = 0; m < 50; m++) { lg[m] = __expf(lg[m] - mx); sum += lg[m]; }
    float inv = 1.0f / sum;
#pragma unroll
    for (int m = 0; m < 50; m++) wtile[tid * 50 + m] = f2bf(lg[m] * inv);

    __syncthreads();

    int wave = tid >> 6, lane = tid & 63;
    int wave_ctok0 = blockIdx.x * 256 + wave * 64;
    const uint4* src = (const uint4*)(wtile + wave * 3200);
    uint4* dst = (uint4*)(w_out + (size_t)wave_ctok0 * 50);
    for (int c = lane; c < 400; c += 64) dst[c] = src[c];
}

// ---------------- kernel 2: fused ve-gather + erase/add MFMA GEMM + activations (bf16 out) ----------------
__global__ __launch_bounds__(256) void k_gemm_ea(const int* __restrict__ q_data,
                                                 const int* __restrict__ r_data,
                                                 const float* __restrict__ vW,
                                                 const float* __restrict__ vb,
                                                 const u16* __restrict__ Wt,
                                                 const float* __restrict__ eb,
                                                 const float* __restrict__ ab,
                                                 u16* __restrict__ e_out,
                                                 u16* __restrict__ a_out,
                                                 int t0, int tcl2) {
    __shared__ __align__(16) u16 lA[128 * 32];
    __shared__ __align__(16) u16 lB[128 * 32];
    __shared__ int s_idx[128];
    __shared__ float s_rs[128];
    __shared__ float s_valf[128];
    __shared__ float s_vb[256];

    int tid = threadIdx.x;
    int row0 = blockIdx.x * 128;   // ctok space
    int col0 = blockIdx.y * 128;

    if (tid < 128) {
        int ctok = row0 + tid;
        int b = ctok >> tcl2;
        int tc = ctok & ((1 << tcl2) - 1);
        int gtok = (b << 9) + t0 + tc;
        int q = q_data[gtok];
        s_idx[tid] = (q > 0) ? (q - 1) : 0;
        s_rs[tid] = (float)r_data[gtok] * 0.25f;
        s_valf[tid] = (q > 0) ? 1.0f : 0.0f;
    }
    s_vb[tid] = vb[tid];

    int wave = tid >> 6, lane = tid & 63;
    int wm = wave >> 1, wn = wave & 1;
    int rl = lane & 15, quad = lane >> 4;
    fx4 acc[4][4] = {};
    __syncthreads();

    for (int k0 = 0; k0 < 256; k0 += 32) {
#pragma unroll
        for (int h = 0; h < 2; h++) {
            int c = tid + h * 256;
            int row = c >> 2, j = c & 3;
            const float* pa = vW + (size_t)s_idx[row] * 256 + k0 + j * 8;
            const float* pb = pa + NQv * 256;
            float4 a0 = ((const float4*)pa)[0];
            float4 a1 = ((const float4*)pa)[1];
            float4 b0 = ((const float4*)pb)[0];
            float4 b1 = ((const float4*)pb)[1];
            float vf = s_valf[row], rs = s_rs[row];
            const float* vbp = &s_vb[k0 + j * 8];
            float o0 = vf * fmaf(rs, b0.x, a0.x) + vbp[0];
            float o1 = vf * fmaf(rs, b0.y, a0.y) + vbp[1];
            float o2 = vf * fmaf(rs, b0.z, a0.z) + vbp[2];
            float o3 = vf * fmaf(rs, b0.w, a0.w) + vbp[3];
            float o4 = vf * fmaf(rs, b1.x, a1.x) + vbp[4];
            float o5 = vf * fmaf(rs, b1.y, a1.y) + vbp[5];
            float o6 = vf * fmaf(rs, b1.z, a1.z) + vbp[6];
            float o7 = vf * fmaf(rs, b1.w, a1.w) + vbp[7];
            uint4 o;
            o.x = pack2(o0, o1); o.y = pack2(o2, o3);
            o.z = pack2(o4, o5); o.w = pack2(o6, o7);
            *(uint4*)(lA + (size_t)c * 8) = o;
        }
#pragma unroll
        for (int h = 0; h < 2; h++) {
            int c = tid + h * 256;
            int n = c >> 2, j = c & 3;
            uint4 u = *(const uint4*)(Wt + (size_t)(col0 + n) * 256 + k0 + j * 8);
            *(uint4*)(lB + (size_t)c * 8) = u;
        }
        __syncthreads();
        bf16x8 af[4], bfr[4];
#pragma unroll
        for (int i = 0; i < 4; i++) af[i] = *(const bf16x8*)(lA + (wm * 64 + i * 16 + rl) * 32 + quad * 8);
#pragma unroll
        for (int j = 0; j < 4; j++) bfr[j] = *(const bf16x8*)(lB + (wn * 64 + j * 16 + rl) * 32 + quad * 8);
#pragma unroll
        for (int i = 0; i < 4; i++)
#pragma unroll
            for (int j = 0; j < 4; j++)
                acc[i][j] = __builtin_amdgcn_mfma_f32_16x16x32_bf16(af[i], bfr[j], acc[i][j], 0, 0, 0);
        __syncthreads();
    }

    bool is_er = (col0 < 256);
    const float* bias = is_er ? eb : ab;
    u16* outp = is_er ? e_out : a_out;
    int cb0 = is_er ? col0 : (col0 - 256);
#pragma unroll
    for (int j = 0; j < 4; j++) {
        int n = cb0 + wn * 64 + j * 16 + rl;
        float bv = bias[n];
#pragma unroll
        for (int i = 0; i < 4; i++) {
            int rowb = row0 + wm * 64 + i * 16 + quad * 4;
#pragma unroll
            for (int r = 0; r < 4; r++) {
                float x = acc[i][j][r] + bv;
                float y = is_er ? sigm(x) : tanh_fast(x);
                outp[(size_t)(rowb + r) * 256 + n] = f2bf(y);
            }
        }
    }
}

// ---------------- kernel 3: scan, 8-step groups, double-buffered w, deep e/a prefetch ----------------
// e_buf and reads_out alias on purpose.
__global__ __launch_bounds__(256) void k_scan(const u16* __restrict__ w_buf,
                                              const u16* e_buf,
                                              const u16* __restrict__ a_buf,
                                              const float* __restrict__ Mv0,
                                              u16* __restrict__ Mv_state,
                                              u16* reads_out,
                                              int Tc, int first, int store) {
    int b = blockIdx.x;
    int tid = threadIdx.x;
    __shared__ float wls[2][8][52];

    float Mv[50];
    if (first) {
#pragma unroll
        for (int m = 0; m < 50; m++) Mv[m] = Mv0[m * 256 + tid];
    } else {
#pragma unroll
        for (int m = 0; m < 50; m++) Mv[m] = bf2f(Mv_state[((size_t)b * 50 + m) * 256 + tid]);
    }

    size_t base = (size_t)b * Tc;
    int ngrp = Tc >> 3;

    // preload group 0
    u16 eu[8], au[8];
#pragma unroll
    for (int s = 0; s < 8; s++) {
        eu[s] = e_buf[(base + s) * 256 + tid];
        au[s] = a_buf[(base + s) * 256 + tid];
    }
    if (tid < 200) {
        u32 w0 = ((const u32*)(w_buf + base * 50))[tid];
        int s = tid / 25, m = (tid % 25) * 2;
        wls[0][s][m] = bflo(w0);
        wls[0][s][m + 1] = bfhi(w0);
    }
    __syncthreads();

    for (int g = 0; g < ngrp; g++) {
        int cur = g & 1, nxt = cur ^ 1;
        bool has_next = (g + 1 < ngrp);
        size_t nbase = base + (size_t)(g + 1) * 8;

        // issue prefetch for next group (predicated)
        u16 eun[8], aun[8];
        u32 wn_ = 0;
        if (has_next) {
#pragma unroll
            for (int s = 0; s < 8; s++) {
                eun[s] = e_buf[(nbase + s) * 256 + tid];
                aun[s] = a_buf[(nbase + s) * 256 + tid];
            }
            if (tid < 200) wn_ = ((const u32*)(w_buf + nbase * 50))[tid];
        }

        // compute 8 steps of current group (no barriers inside)
#pragma unroll
        for (int s = 0; s < 8; s++) {
            float e = bf2f(eu[s]), a = bf2f(au[s]);
            const float* wv = wls[cur][s];
            float rd = 0.f;
#pragma unroll
            for (int m = 0; m < 50; m++) {
                float wm = wv[m];
                rd = fmaf(wm, Mv[m], rd);                 // read BEFORE write
                float tmp = fmaf(-e, Mv[m], a);           // a - e*Mv
                Mv[m] = fmaf(wm, tmp, Mv[m]);             // Mv + w*(a - e*Mv)
            }
            reads_out[(base + g * 8 + s) * 256 + tid] = f2bf(rd);
        }

        if (has_next) {
            if (tid < 200) {
                int s = tid / 25, m = (tid % 25) * 2;
                wls[nxt][s][m] = bflo(wn_);
                wls[nxt][s][m + 1] = bfhi(wn_);
            }
#pragma unroll
            for (int s = 0; s < 8; s++) { eu[s] = eun[s]; au[s] = aun[s]; }
        }
        __syncthreads();
    }

    if (store) {
#pragma unroll
        for (int m = 0; m < 50; m++) Mv_state[((size_t)b * 50 + m) * 256 + tid] = f2bf(Mv[m]);
    }
}

// ---------------- kernel 4: fused summary MFMA + heads (fp32 out) ----------------
__global__ __launch_bounds__(256) void k_sum_heads(const u16* __restrict__ reads,
                                                   const int* __restrict__ q_data,
                                                   const float* __restrict__ qeW,
                                                   const u16* __restrict__ SWt,
                                                   const float* __restrict__ sb,
                                                   const float* __restrict__ abilW,
                                                   const float* __restrict__ abilb,
                                                   const float* __restrict__ tW,
                                                   const float* __restrict__ tb,
                                                   const float* __restrict__ dW,
                                                   const float* __restrict__ db,
                                                   const float* __restrict__ cW,
                                                   const float* __restrict__ cb,
                                                   float* __restrict__ out,
                                                   int t0, int tcl2) {
    __shared__ __align__(16) u16 lA[128 * 32];
    __shared__ __align__(16) u16 lB[64 * 32];
    __shared__ float sS[128 * 52];
    __shared__ int s_q[128];
    int tid = threadIdx.x;
    int row0 = blockIdx.x * 128;
    if (tid < 128) {
        int ctok = row0 + tid;
        int b = ctok >> tcl2;
        int tc = ctok & ((1 << tcl2) - 1);
        s_q[tid] = q_data[(b << 9) + t0 + tc];
    }
    int wave = tid >> 6, lane = tid & 63;
    int wm = wave >> 1, wn = wave & 1;
    int rl = lane & 15, quad = lane >> 4;
    fx4 acc[4][2] = {};
    __syncthreads();

    for (int ks = 0; ks < 10; ks++) {
        int k0 = ks * 32;
#pragma unroll
        for (int h = 0; h < 2; h++) {
            int c = tid + h * 256;
            int row = c >> 2, j = c & 3;
            if (k0 < 256) {
                uint4 u = *(const uint4*)(reads + (size_t)(row0 + row) * 256 + k0 + j * 8);
                *(uint4*)(lA + (size_t)c * 8) = u;
            } else {
                const float* src = qeW + (size_t)s_q[row] * 64 + (k0 - 256) + j * 8;
                float4 f0 = ((const float4*)src)[0];
                float4 f1 = ((const float4*)src)[1];
                uint4 o;
                o.x = pack2(f0.x, f0.y); o.y = pack2(f0.z, f0.w);
                o.z = pack2(f1.x, f1.y); o.w = pack2(f1.z, f1.w);
                *(uint4*)(lA + (size_t)c * 8) = o;
            }
        }
        {
            int c = tid, n = c >> 2, j = c & 3;
            uint4 u = *(const uint4*)(SWt + (size_t)n * 320 + k0 + j * 8);
            *(uint4*)(lB + (size_t)c * 8) = u;
        }
        __syncthreads();
        bf16x8 af[4], bfr[2];
#pragma unroll
        for (int i = 0; i < 4; i++) af[i] = *(const bf16x8*)(lA + (wm * 64 + i * 16 + rl) * 32 + quad * 8);
#pragma unroll
        for (int j = 0; j < 2; j++) bfr[j] = *(const bf16x8*)(lB + (wn * 32 + j * 16 + rl) * 32 + quad * 8);
#pragma unroll
        for (int i = 0; i < 4; i++)
#pragma unroll
            for (int j = 0; j < 2; j++)
                acc[i][j] = __builtin_amdgcn_mfma_f32_16x16x32_bf16(af[i], bfr[j], acc[i][j], 0, 0, 0);
        __syncthreads();
    }

    // epilogue: S tile -> LDS (fp32)
#pragma unroll
    for (int j = 0; j < 2; j++) {
        int n = wn * 32 + j * 16 + rl;
        if (n < 50) {
            float bv = sb[n];
#pragma unroll
            for (int i = 0; i < 4; i++) {
                int rowl = wm * 64 + i * 16 + quad * 4;
#pragma unroll
                for (int r = 0; r < 4; r++)
                    sS[(rowl + r) * 52 + n] = tanh_fast(acc[i][j][r] + bv);
            }
        }
    }
    __syncthreads();

    // heads: one thread per token (threads 0..127)
    if (tid < 128) {
        int ctok = row0 + tid;
        int b = ctok >> tcl2;
        int tc = ctok & ((1 << tcl2) - 1);
        int gtok = (b << 9) + t0 + tc;
        const float* sp = &sS[tid * 52];

        float qe[64];
        const float4* qr = (const float4*)(qeW + (size_t)s_q[tid] * 64);
#pragma unroll
        for (int i = 0; i < 16; i++) {
            float4 u = qr[i];
            qe[4 * i + 0] = u.x; qe[4 * i + 1] = u.y;
            qe[4 * i + 2] = u.z; qe[4 * i + 3] = u.w;
        }
        float th = abilb[0];
#pragma unroll
        for (int j = 0; j < 50; j++) th = fmaf(sp[j], abilW[j], th);
        out[gtok] = th * 3.0f;

        float bt0 = tb[0], bt1 = tb[1], bt2 = tb[2], bt3 = tb[3];
#pragma unroll
        for (int k = 0; k < 64; k++) {
            float x = qe[k];
            bt0 = fmaf(x, tW[k * 4 + 0], bt0);
            bt1 = fmaf(x, tW[k * 4 + 1], bt1);
            bt2 = fmaf(x, tW[k * 4 + 2], bt2);
            bt3 = fmaf(x, tW[k * 4 + 3], bt3);
        }
        out[NT + (size_t)gtok * 4 + 0] = bt0;
        out[NT + (size_t)gtok * 4 + 1] = bt1;
        out[NT + (size_t)gtok * 4 + 2] = bt2;
        out[NT + (size_t)gtok * 4 + 3] = bt3;

        float da = db[0];
        float l0 = cb[0], l1 = cb[1], l2 = cb[2], l3 = cb[3];
#pragma unroll
        for (int i = 0; i < 50; i++) {
            float x = sp[i];
            da = fmaf(x, dW[i], da);
            l0 = fmaf(x, cW[i * 4 + 0], l0);
            l1 = fmaf(x, cW[i * 4 + 1], l1);
            l2 = fmaf(x, cW[i * 4 + 2], l2);
            l3 = fmaf(x, cW[i * 4 + 3], l3);
        }
#pragma unroll
        for (int k = 0; k < 64; k++) {
            float x = qe[k];
            int i = 50 + k;
            da = fmaf(x, dW[i], da);
            l0 = fmaf(x, cW[i * 4 + 0], l0);
            l1 = fmaf(x, cW[i * 4 + 1], l1);
            l2 = fmaf(x, cW[i * 4 + 2], l2);
            l3 = fmaf(x, cW[i * 4 + 3], l3);
        }
        float alpha = logf(1.0f + __expf(da));
        out[5 * (size_t)NT + gtok] = alpha;

        out[11 * (size_t)NT + (size_t)gtok * 4 + 0] = l0;
        out[11 * (size_t)NT + (size_t)gtok * 4 + 1] = l1;
        out[11 * (size_t)NT + (size_t)gtok * 4 + 2] = l2;
        out[11 * (size_t)NT + (size_t)gtok * 4 + 3] = l3;

        float c0 = sigm(l0);
        float c1 = c0 * sigm(l1);
        float c2 = c1 * sigm(l2);
        float c3 = c2 * sigm(l3);
        size_t pb = 6 * (size_t)NT + (size_t)gtok * 5;
        out[pb + 0] = 1.0f - c0;
        out[pb + 1] = c0 - c1;
        out[pb + 2] = c1 - c2;
        out[pb + 3] = c2 - c3;
        out[pb + 4] = c3;
    }
}

extern "C" void kernel_launch(void* const* d_in, const int* in_sizes, int n_in,
                              void* d_out, int out_size, void* d_ws, size_t ws_size,
                              hipStream_t stream) {
    (void)in_sizes; (void)n_in; (void)out_size;
    const int* q_data = (const int*)d_in[0];
    const int* r_data = (const int*)d_in[1];
    const float* qeW = (const float*)d_in[2];
    const float* Mk  = (const float*)d_in[3];
    const float* Mv0 = (const float*)d_in[4];
    const float* vW  = (const float*)d_in[5];
    const float* vb  = (const float*)d_in[6];
    const float* eW  = (const float*)d_in[7];
    const float* eb  = (const float*)d_in[8];
    const float* aW  = (const float*)d_in[9];
    const float* ab  = (const float*)d_in[10];
    const float* sW  = (const float*)d_in[11];
    const float* sb  = (const float*)d_in[12];
    const float* abilW = (const float*)d_in[13];
    const float* abilb = (const float*)d_in[14];
    const float* tW  = (const float*)d_in[15];
    const float* tb  = (const float*)d_in[16];
    const float* dW  = (const float*)d_in[17];
    const float* db  = (const float*)d_in[18];
    const float* cW  = (const float*)d_in[19];
    const float* cb  = (const float*)d_in[20];

    // bf16 workspace. footprint(Tc) = 13,410,304 + 575,488*Tc bytes
    int Tc = 8;
    const int cands[4] = {64, 32, 16, 8};
    for (int i = 0; i < 4; i++) {
        size_t need = 13410304ULL + 575488ULL * (size_t)cands[i];
        if (need <= ws_size) { Tc = cands[i]; break; }
    }
    int tcl2 = 31 - __builtin_clz((u32)Tc);
    int nch = T_LEN / Tc;

    char* ws = (char*)d_ws;
    u16* Wt    = (u16*)(ws + 0);                          // 262,144 B
    u16* SWt   = (u16*)(ws + 262144);                     // 40,960 B
    u16* MvSt  = (u16*)(ws + 303104);                     // 13,107,200 B (bf16 state)
    u16* w_c   = (u16*)(ws + 13410304);                   // 51,200*Tc B
    u16* e_c   = (u16*)(ws + 13410304 + 51200ULL * Tc);   // 262,144*Tc B (alias reads)
    u16* a_c   = (u16*)(ws + 13410304 + 313344ULL * Tc);  // 262,144*Tc B
    u16* reads = e_c;
    float* out = (float*)d_out;

    int rows = B_SZ * Tc;

    k_prep_w<<<592, 256, 0, stream>>>(eW, aW, sW, Wt, SWt);
    for (int c = 0; c < nch; c++) {
        int t0 = c * Tc;
        k_w<<<rows / 256, 256, 0, stream>>>(q_data, qeW, Mk, w_c, t0, tcl2);
        dim3 g2(rows / 128, 4);
        k_gemm_ea<<<g2, 256, 0, stream>>>(q_data, r_data, vW, vb, Wt, eb, ab, e_c, a_c, t0, tcl2);
        k_scan<<<B_SZ, 256, 0, stream>>>(w_c, e_c, a_c, Mv0, MvSt, reads, Tc,
                                         (c == 0) ? 1 : 0, (c < nch - 1) ? 1 : 0);
        k_sum_heads<<<rows / 128, 256, 0, stream>>>(reads, q_data, qeW, SWt, sb,
                                                    abilW, abilb, tW, tb, dW, db, cW, cb,
                                                    out, t0, tcl2);
    }
}

// Round 10
// 855.823 us; speedup vs baseline: 5.1888x; 1.2061x over previous
//
#include <hip/hip_runtime.h>

typedef unsigned short u16;
typedef unsigned int u32;
typedef __bf16 bf16x8 __attribute__((ext_vector_type(8)));
typedef float fx4 __attribute__((ext_vector_type(4)));

#define NT 262144      // B*T global tokens
#define B_SZ 512
#define T_LEN 512
#define NQv 1000
#define LP 40          // padded LDS row stride in u16 (80 B = 5*16, b128-aligned, 2-way banks)

__device__ __forceinline__ float bf2f(u16 u) { return __uint_as_float(((u32)u) << 16); }
__device__ __forceinline__ float bflo(u32 u) { return __uint_as_float(u << 16); }
__device__ __forceinline__ float bfhi(u32 u) { return __uint_as_float(u & 0xffff0000u); }
__device__ __forceinline__ u16 f2bf(float f) {
    u32 x = __float_as_uint(f);
    x += 0x7fffu + ((x >> 16) & 1u);
    return (u16)(x >> 16);
}
__device__ __forceinline__ u32 pack2(float a, float b) {
    return (u32)f2bf(a) | ((u32)f2bf(b) << 16);
}
__device__ __forceinline__ float sigm(float x) { return 1.0f / (1.0f + __expf(-x)); }
__device__ __forceinline__ float tanh_fast(float x) {
    float e2 = __expf(2.0f * x);
    return 1.0f - 2.0f / (e2 + 1.0f);   // safe at +inf
}

// ---------------- kernel 0: transpose fp32 weights -> k-contiguous bf16 B layouts ----------------
__global__ __launch_bounds__(256) void k_prep_w(const float* __restrict__ eW,
                                                const float* __restrict__ aW,
                                                const float* __restrict__ sW,
                                                u16* __restrict__ Wt,
                                                u16* __restrict__ SWt) {
    int id = blockIdx.x * 256 + threadIdx.x;
    if (id < 131072) {
        int n = id >> 8, k = id & 255;
        Wt[n * 256 + k] = f2bf((n < 256) ? eW[k * 256 + n] : aW[k * 256 + (n - 256)]);
    } else {
        int id2 = id - 131072;
        if (id2 < 64 * 320) {
            int n = id2 / 320, k = id2 - n * 320;
            SWt[n * 320 + k] = (n < 50) ? f2bf(sW[k * 50 + n]) : (u16)0;
        }
    }
}

// ---------------- kernel 1: per-chunk-token softmax attention w [ctok][50] (bf16 out) ----------------
__global__ __launch_bounds__(256) void k_w(const int* __restrict__ q_data,
                                           const float* __restrict__ qeW,
                                           const float* __restrict__ Mk,
                                           u16* __restrict__ w_out,
                                           int t0, int tcl2) {
    __shared__ __align__(16) float mk[3200];       // Mk fp32 [50][64]
    __shared__ __align__(16) u16 wtile[256 * 50];
    int tid = threadIdx.x;
    for (int i = tid; i < 3200; i += 256) mk[i] = Mk[i];

    int ctok = blockIdx.x * 256 + tid;
    int b = ctok >> tcl2;
    int tc = ctok & ((1 << tcl2) - 1);
    int gtok = (b << 9) + t0 + tc;
    int q = q_data[gtok];

    float qe[64];
    {
        const float4* qr = (const float4*)(qeW + (size_t)q * 64);
#pragma unroll
        for (int i = 0; i < 16; i++) {
            float4 u = qr[i];
            qe[4 * i + 0] = u.x; qe[4 * i + 1] = u.y;
            qe[4 * i + 2] = u.z; qe[4 * i + 3] = u.w;
        }
    }
    __syncthreads();

    float lg[50];
#pragma unroll
    for (int m = 0; m < 50; m++) {
        const float* mr = &mk[m * 64];
        float acc = 0.f;
#pragma unroll
        for (int k = 0; k < 64; k++) acc = fmaf(qe[k], mr[k], acc);
        lg[m] = acc;
    }
    float mx = -1e30f;
#pragma unroll
    for (int m = 0; m < 50; m++) mx = fmaxf(mx, lg[m]);
    float sum = 0.f;
#pragma unroll
    for (int m = 0; m < 50; m++) { lg[m] = __expf(lg[m] - mx); sum += lg[m]; }
    float inv = 1.0f / sum;
#pragma unroll
    for (int m = 0; m < 50; m++) wtile[tid * 50 + m] = f2bf(lg[m] * inv);

    __syncthreads();

    int wave = tid >> 6, lane = tid & 63;
    int wave_ctok0 = blockIdx.x * 256 + wave * 64;
    const uint4* src = (const uint4*)(wtile + wave * 3200);
    uint4* dst = (uint4*)(w_out + (size_t)wave_ctok0 * 50);
    for (int c = lane; c < 400; c += 64) dst[c] = src[c];
}

// ---------------- kernel 2: fused ve-gather + erase/add MFMA GEMM, pipelined, padded LDS ----------------
__global__ __launch_bounds__(256) void k_gemm_ea(const int* __restrict__ q_data,
                                                 const int* __restrict__ r_data,
                                                 const float* __restrict__ vW,
                                                 const float* __restrict__ vb,
                                                 const u16* __restrict__ Wt,
                                                 const float* __restrict__ eb,
                                                 const float* __restrict__ ab,
                                                 u16* __restrict__ e_out,
                                                 u16* __restrict__ a_out,
                                                 int t0, int tcl2) {
    __shared__ __align__(16) u16 smem[2 * 128 * LP];   // lA | lB ; reused as 64x128 C-stage
    u16* lA = smem;
    u16* lB = smem + 128 * LP;
    __shared__ int s_idx[128];
    __shared__ float s_rs[128];
    __shared__ float s_valf[128];
    __shared__ float s_vb[256];

    int tid = threadIdx.x;
    int row0 = blockIdx.x * 128;   // ctok space
    int col0 = blockIdx.y * 128;

    if (tid < 128) {
        int ctok = row0 + tid;
        int b = ctok >> tcl2;
        int tc = ctok & ((1 << tcl2) - 1);
        int gtok = (b << 9) + t0 + tc;
        int q = q_data[gtok];
        s_idx[tid] = (q > 0) ? (q - 1) : 0;
        s_rs[tid] = (float)r_data[gtok] * 0.25f;
        s_valf[tid] = (q > 0) ? 1.0f : 0.0f;
    }
    s_vb[tid] = vb[tid];

    int wave = tid >> 6, lane = tid & 63;
    int wm = wave >> 1, wn = wave & 1;
    int rl = lane & 15, quad = lane >> 4;
    int crow = tid >> 2, cj = tid & 3;          // this thread's two staging slots: (crow,cj),(crow+64,cj)
    fx4 acc[4][4] = {};
    __syncthreads();

    // prefetch registers for gather + B tile
    float4 fa0[2], fa1[2], fb0[2], fb1[2];
    uint4 uB[2];
#define ISSUE(K)                                                                   \
    {                                                                              \
        _Pragma("unroll")                                                          \
        for (int h = 0; h < 2; h++) {                                              \
            int row = crow + h * 64;                                               \
            const float* pa = vW + (size_t)s_idx[row] * 256 + (K) + cj * 8;        \
            fa0[h] = ((const float4*)pa)[0];                                       \
            fa1[h] = ((const float4*)pa)[1];                                       \
            const float* pb = pa + NQv * 256;                                      \
            fb0[h] = ((const float4*)pb)[0];                                       \
            fb1[h] = ((const float4*)pb)[1];                                       \
            uB[h] = *(const uint4*)(Wt + (size_t)(col0 + row) * 256 + (K) + cj * 8); \
        }                                                                          \
    }

    ISSUE(0)
    for (int k0 = 0; k0 < 256; k0 += 32) {
        // stage prefetched regs -> LDS (bf16 pack for A)
#pragma unroll
        for (int h = 0; h < 2; h++) {
            int row = crow + h * 64;
            float vf = s_valf[row], rs = s_rs[row];
            const float* vbp = &s_vb[k0 + cj * 8];
            float o0 = vf * fmaf(rs, fb0[h].x, fa0[h].x) + vbp[0];
            float o1 = vf * fmaf(rs, fb0[h].y, fa0[h].y) + vbp[1];
            float o2 = vf * fmaf(rs, fb0[h].z, fa0[h].z) + vbp[2];
            float o3 = vf * fmaf(rs, fb0[h].w, fa0[h].w) + vbp[3];
            float o4 = vf * fmaf(rs, fb1[h].x, fa1[h].x) + vbp[4];
            float o5 = vf * fmaf(rs, fb1[h].y, fa1[h].y) + vbp[5];
            float o6 = vf * fmaf(rs, fb1[h].z, fa1[h].z) + vbp[6];
            float o7 = vf * fmaf(rs, fb1[h].w, fa1[h].w) + vbp[7];
            uint4 o;
            o.x = pack2(o0, o1); o.y = pack2(o2, o3);
            o.z = pack2(o4, o5); o.w = pack2(o6, o7);
            *(uint4*)(lA + row * LP + cj * 8) = o;
            *(uint4*)(lB + row * LP + cj * 8) = uB[h];
        }
        __syncthreads();
        if (k0 < 224) ISSUE(k0 + 32)   // overlap next gather with MFMA
        bf16x8 af[4], bfr[4];
#pragma unroll
        for (int i = 0; i < 4; i++) af[i] = *(const bf16x8*)(lA + (wm * 64 + i * 16 + rl) * LP + quad * 8);
#pragma unroll
        for (int j = 0; j < 4; j++) bfr[j] = *(const bf16x8*)(lB + (wn * 64 + j * 16 + rl) * LP + quad * 8);
#pragma unroll
        for (int i = 0; i < 4; i++)
#pragma unroll
            for (int j = 0; j < 4; j++)
                acc[i][j] = __builtin_amdgcn_mfma_f32_16x16x32_bf16(af[i], bfr[j], acc[i][j], 0, 0, 0);
        __syncthreads();
    }
#undef ISSUE

    // coalesced epilogue via LDS C-stage (64 rows x 128 cols per half)
    bool is_er = (col0 < 256);
    const float* bias = is_er ? eb : ab;
    u16* outp = is_er ? e_out : a_out;
    int cb0 = col0 & 255;
    u16* cst = smem;   // 8192 u16
#pragma unroll
    for (int h = 0; h < 2; h++) {
        if (wm == h) {
#pragma unroll
            for (int j = 0; j < 4; j++) {
                int nl = wn * 64 + j * 16 + rl;
                float bv = bias[cb0 + nl];
#pragma unroll
                for (int i = 0; i < 4; i++) {
                    int rowl = i * 16 + quad * 4;
#pragma unroll
                    for (int r = 0; r < 4; r++) {
                        float x = acc[i][j][r] + bv;
                        cst[(rowl + r) * 128 + nl] = f2bf(is_er ? sigm(x) : tanh_fast(x));
                    }
                }
            }
        }
        __syncthreads();
#pragma unroll
        for (int c = 0; c < 4; c++) {
            int idx = c * 256 + tid;
            int row = idx >> 4, seg = idx & 15;
            *(uint4*)(outp + (size_t)(row0 + h * 64 + row) * 256 + cb0 + seg * 8) =
                *(const uint4*)(cst + row * 128 + seg * 8);
        }
        __syncthreads();
    }
}

// ---------------- kernel 3: scan, 8-step groups, double-buffered w, deep e/a prefetch ----------------
// e_buf and reads_out alias on purpose.
__global__ __launch_bounds__(256) void k_scan(const u16* __restrict__ w_buf,
                                              const u16* e_buf,
                                              const u16* __restrict__ a_buf,
                                              const float* __restrict__ Mv0,
                                              u16* __restrict__ Mv_state,
                                              u16* reads_out,
                                              int Tc, int first, int store) {
    int b = blockIdx.x;
    int tid = threadIdx.x;
    __shared__ float wls[2][8][52];

    float Mv[50];
    if (first) {
#pragma unroll
        for (int m = 0; m < 50; m++) Mv[m] = Mv0[m * 256 + tid];
    } else {
#pragma unroll
        for (int m = 0; m < 50; m++) Mv[m] = bf2f(Mv_state[((size_t)b * 50 + m) * 256 + tid]);
    }

    size_t base = (size_t)b * Tc;
    int ngrp = Tc >> 3;

    u16 eu[8], au[8];
#pragma unroll
    for (int s = 0; s < 8; s++) {
        eu[s] = e_buf[(base + s) * 256 + tid];
        au[s] = a_buf[(base + s) * 256 + tid];
    }
    if (tid < 200) {
        u32 w0 = ((const u32*)(w_buf + base * 50))[tid];
        int s = tid / 25, m = (tid % 25) * 2;
        wls[0][s][m] = bflo(w0);
        wls[0][s][m + 1] = bfhi(w0);
    }
    __syncthreads();

    for (int g = 0; g < ngrp; g++) {
        int cur = g & 1, nxt = cur ^ 1;
        bool has_next = (g + 1 < ngrp);
        size_t nbase = base + (size_t)(g + 1) * 8;

        u16 eun[8], aun[8];
        u32 wn_ = 0;
        if (has_next) {
#pragma unroll
            for (int s = 0; s < 8; s++) {
                eun[s] = e_buf[(nbase + s) * 256 + tid];
                aun[s] = a_buf[(nbase + s) * 256 + tid];
            }
            if (tid < 200) wn_ = ((const u32*)(w_buf + nbase * 50))[tid];
        }

#pragma unroll
        for (int s = 0; s < 8; s++) {
            float e = bf2f(eu[s]), a = bf2f(au[s]);
            const float* wv = wls[cur][s];
            float rd = 0.f;
#pragma unroll
            for (int m = 0; m < 50; m++) {
                float wm = wv[m];
                rd = fmaf(wm, Mv[m], rd);                 // read BEFORE write
                float tmp = fmaf(-e, Mv[m], a);           // a - e*Mv
                Mv[m] = fmaf(wm, tmp, Mv[m]);             // Mv + w*(a - e*Mv)
            }
            reads_out[(base + g * 8 + s) * 256 + tid] = f2bf(rd);
        }

        if (has_next) {
            if (tid < 200) {
                int s = tid / 25, m = (tid % 25) * 2;
                wls[nxt][s][m] = bflo(wn_);
                wls[nxt][s][m + 1] = bfhi(wn_);
            }
#pragma unroll
            for (int s = 0; s < 8; s++) { eu[s] = eun[s]; au[s] = aun[s]; }
        }
        __syncthreads();
    }

    if (store) {
#pragma unroll
        for (int m = 0; m < 50; m++) Mv_state[((size_t)b * 50 + m) * 256 + tid] = f2bf(Mv[m]);
    }
}

// ---------------- kernel 4: fused summary MFMA + heads (fp32 out), padded LDS ----------------
__global__ __launch_bounds__(256) void k_sum_heads(const u16* __restrict__ reads,
                                                   const int* __restrict__ q_data,
                                                   const float* __restrict__ qeW,
                                                   const u16* __restrict__ SWt,
                                                   const float* __restrict__ sb,
                                                   const float* __restrict__ abilW,
                                                   const float* __restrict__ abilb,
                                                   const float* __restrict__ tW,
                                                   const float* __restrict__ tb,
                                                   const float* __restrict__ dW,
                                                   const float* __restrict__ db,
                                                   const float* __restrict__ cW,
                                                   const float* __restrict__ cb,
                                                   float* __restrict__ out,
                                                   int t0, int tcl2) {
    __shared__ __align__(16) u16 lA[128 * LP];
    __shared__ __align__(16) u16 lB[64 * LP];
    __shared__ float sS[128 * 52];
    __shared__ int s_q[128];
    int tid = threadIdx.x;
    int row0 = blockIdx.x * 128;
    if (tid < 128) {
        int ctok = row0 + tid;
        int b = ctok >> tcl2;
        int tc = ctok & ((1 << tcl2) - 1);
        s_q[tid] = q_data[(b << 9) + t0 + tc];
    }
    int wave = tid >> 6, lane = tid & 63;
    int wm = wave >> 1, wn = wave & 1;
    int rl = lane & 15, quad = lane >> 4;
    fx4 acc[4][2] = {};
    __syncthreads();

    for (int ks = 0; ks < 10; ks++) {
        int k0 = ks * 32;
#pragma unroll
        for (int h = 0; h < 2; h++) {
            int c = tid + h * 256;
            int row = c >> 2, j = c & 3;
            if (k0 < 256) {
                uint4 u = *(const uint4*)(reads + (size_t)(row0 + row) * 256 + k0 + j * 8);
                *(uint4*)(lA + row * LP + j * 8) = u;
            } else {
                const float* src = qeW + (size_t)s_q[row] * 64 + (k0 - 256) + j * 8;
                float4 f0 = ((const float4*)src)[0];
                float4 f1 = ((const float4*)src)[1];
                uint4 o;
                o.x = pack2(f0.x, f0.y); o.y = pack2(f0.z, f0.w);
                o.z = pack2(f1.x, f1.y); o.w = pack2(f1.z, f1.w);
                *(uint4*)(lA + row * LP + j * 8) = o;
            }
        }
        {
            int n = tid >> 2, j = tid & 3;
            uint4 u = *(const uint4*)(SWt + (size_t)n * 320 + k0 + j * 8);
            *(uint4*)(lB + n * LP + j * 8) = u;
        }
        __syncthreads();
        bf16x8 af[4], bfr[2];
#pragma unroll
        for (int i = 0; i < 4; i++) af[i] = *(const bf16x8*)(lA + (wm * 64 + i * 16 + rl) * LP + quad * 8);
#pragma unroll
        for (int j = 0; j < 2; j++) bfr[j] = *(const bf16x8*)(lB + (wn * 32 + j * 16 + rl) * LP + quad * 8);
#pragma unroll
        for (int i = 0; i < 4; i++)
#pragma unroll
            for (int j = 0; j < 2; j++)
                acc[i][j] = __builtin_amdgcn_mfma_f32_16x16x32_bf16(af[i], bfr[j], acc[i][j], 0, 0, 0);
        __syncthreads();
    }

#pragma unroll
    for (int j = 0; j < 2; j++) {
        int n = wn * 32 + j * 16 + rl;
        if (n < 50) {
            float bv = sb[n];
#pragma unroll
            for (int i = 0; i < 4; i++) {
                int rowl = wm * 64 + i * 16 + quad * 4;
#pragma unroll
                for (int r = 0; r < 4; r++)
                    sS[(rowl + r) * 52 + n] = tanh_fast(acc[i][j][r] + bv);
            }
        }
    }
    __syncthreads();

    if (tid < 128) {
        int ctok = row0 + tid;
        int b = ctok >> tcl2;
        int tc = ctok & ((1 << tcl2) - 1);
        int gtok = (b << 9) + t0 + tc;
        const float* sp = &sS[tid * 52];

        float qe[64];
        const float4* qr = (const float4*)(qeW + (size_t)s_q[tid] * 64);
#pragma unroll
        for (int i = 0; i < 16; i++) {
            float4 u = qr[i];
            qe[4 * i + 0] = u.x; qe[4 * i + 1] = u.y;
            qe[4 * i + 2] = u.z; qe[4 * i + 3] = u.w;
        }
        float th = abilb[0];
#pragma unroll
        for (int j = 0; j < 50; j++) th = fmaf(sp[j], abilW[j], th);
        out[gtok] = th * 3.0f;

        float bt0 = tb[0], bt1 = tb[1], bt2 = tb[2], bt3 = tb[3];
#pragma unroll
        for (int k = 0; k < 64; k++) {
            float x = qe[k];
            bt0 = fmaf(x, tW[k * 4 + 0], bt0);
            bt1 = fmaf(x, tW[k * 4 + 1], bt1);
            bt2 = fmaf(x, tW[k * 4 + 2], bt2);
            bt3 = fmaf(x, tW[k * 4 + 3], bt3);
        }
        out[NT + (size_t)gtok * 4 + 0] = bt0;
        out[NT + (size_t)gtok * 4 + 1] = bt1;
        out[NT + (size_t)gtok * 4 + 2] = bt2;
        out[NT + (size_t)gtok * 4 + 3] = bt3;

        float da = db[0];
        float l0 = cb[0], l1 = cb[1], l2 = cb[2], l3 = cb[3];
#pragma unroll
        for (int i = 0; i < 50; i++) {
            float x = sp[i];
            da = fmaf(x, dW[i], da);
            l0 = fmaf(x, cW[i * 4 + 0], l0);
            l1 = fmaf(x, cW[i * 4 + 1], l1);
            l2 = fmaf(x, cW[i * 4 + 2], l2);
            l3 = fmaf(x, cW[i * 4 + 3], l3);
        }
#pragma unroll
        for (int k = 0; k < 64; k++) {
            float x = qe[k];
            int i = 50 + k;
            da = fmaf(x, dW[i], da);
            l0 = fmaf(x, cW[i * 4 + 0], l0);
            l1 = fmaf(x, cW[i * 4 + 1], l1);
            l2 = fmaf(x, cW[i * 4 + 2], l2);
            l3 = fmaf(x, cW[i * 4 + 3], l3);
        }
        float alpha = logf(1.0f + __expf(da));
        out[5 * (size_t)NT + gtok] = alpha;

        out[11 * (size_t)NT + (size_t)gtok * 4 + 0] = l0;
        out[11 * (size_t)NT + (size_t)gtok * 4 + 1] = l1;
        out[11 * (size_t)NT + (size_t)gtok * 4 + 2] = l2;
        out[11 * (size_t)NT + (size_t)gtok * 4 + 3] = l3;

        float c0 = sigm(l0);
        float c1 = c0 * sigm(l1);
        float c2 = c1 * sigm(l2);
        float c3 = c2 * sigm(l3);
        size_t pb = 6 * (size_t)NT + (size_t)gtok * 5;
        out[pb + 0] = 1.0f - c0;
        out[pb + 1] = c0 - c1;
        out[pb + 2] = c1 - c2;
        out[pb + 3] = c2 - c3;
        out[pb + 4] = c3;
    }
}

extern "C" void kernel_launch(void* const* d_in, const int* in_sizes, int n_in,
                              void* d_out, int out_size, void* d_ws, size_t ws_size,
                              hipStream_t stream) {
    (void)in_sizes; (void)n_in; (void)out_size;
    const int* q_data = (const int*)d_in[0];
    const int* r_data = (const int*)d_in[1];
    const float* qeW = (const float*)d_in[2];
    const float* Mk  = (const float*)d_in[3];
    const float* Mv0 = (const float*)d_in[4];
    const float* vW  = (const float*)d_in[5];
    const float* vb  = (const float*)d_in[6];
    const float* eW  = (const float*)d_in[7];
    const float* eb  = (const float*)d_in[8];
    const float* aW  = (const float*)d_in[9];
    const float* ab  = (const float*)d_in[10];
    const float* sW  = (const float*)d_in[11];
    const float* sb  = (const float*)d_in[12];
    const float* abilW = (const float*)d_in[13];
    const float* abilb = (const float*)d_in[14];
    const float* tW  = (const float*)d_in[15];
    const float* tb  = (const float*)d_in[16];
    const float* dW  = (const float*)d_in[17];
    const float* db  = (const float*)d_in[18];
    const float* cW  = (const float*)d_in[19];
    const float* cb  = (const float*)d_in[20];

    // bf16 workspace. footprint(Tc) = 13,410,304 + 575,488*Tc bytes (ws ~268 MB observed)
    int Tc = 8;
    const int cands[6] = {256, 128, 64, 32, 16, 8};
    for (int i = 0; i < 6; i++) {
        size_t need = 13410304ULL + 575488ULL * (size_t)cands[i];
        if (need <= ws_size) { Tc = cands[i]; break; }
    }
    int tcl2 = 31 - __builtin_clz((u32)Tc);
    int nch = T_LEN / Tc;

    char* ws = (char*)d_ws;
    u16* Wt    = (u16*)(ws + 0);                          // 262,144 B
    u16* SWt   = (u16*)(ws + 262144);                     // 40,960 B
    u16* MvSt  = (u16*)(ws + 303104);                     // 13,107,200 B (bf16 state)
    u16* w_c   = (u16*)(ws + 13410304);                   // 51,200*Tc B
    u16* e_c   = (u16*)(ws + 13410304 + 51200ULL * Tc);   // 262,144*Tc B (alias reads)
    u16* a_c   = (u16*)(ws + 13410304 + 313344ULL * Tc);  // 262,144*Tc B
    u16* reads = e_c;
    float* out = (float*)d_out;

    int rows = B_SZ * Tc;

    k_prep_w<<<592, 256, 0, stream>>>(eW, aW, sW, Wt, SWt);
    for (int c = 0; c < nch; c++) {
        int t0 = c * Tc;
        k_w<<<rows / 256, 256, 0, stream>>>(q_data, qeW, Mk, w_c, t0, tcl2);
        dim3 g2(rows / 128, 4);
        k_gemm_ea<<<g2, 256, 0, stream>>>(q_data, r_data, vW, vb, Wt, eb, ab, e_c, a_c, t0, tcl2);
        k_scan<<<B_SZ, 256, 0, stream>>>(w_c, e_c, a_c, Mv0, MvSt, reads, Tc,
                                         (c == 0) ? 1 : 0, (c < nch - 1) ? 1 : 0);
        k_sum_heads<<<rows / 128, 256, 0, stream>>>(reads, q_data, qeW, SWt, sb,
                                                    abilW, abilb, tW, tb, dW, db, cW, cb,
                                                    out, t0, tcl2);
    }
}

// Round 11
// 790.231 us; speedup vs baseline: 5.6195x; 1.0830x over previous
//
#include <hip/hip_runtime.h>

typedef unsigned short u16;
typedef unsigned int u32;
typedef __bf16 bf16x8 __attribute__((ext_vector_type(8)));
typedef float fx4 __attribute__((ext_vector_type(4)));

#define NT 262144      // B*T global tokens
#define B_SZ 512
#define T_LEN 512
#define NQv 1000
#define LP 40          // padded LDS stride for k_sum_heads

__device__ __forceinline__ float bf2f(u16 u) { return __uint_as_float(((u32)u) << 16); }
__device__ __forceinline__ float bflo(u32 u) { return __uint_as_float(u << 16); }
__device__ __forceinline__ float bfhi(u32 u) { return __uint_as_float(u & 0xffff0000u); }
__device__ __forceinline__ u16 f2bf(float f) {
    u32 x = __float_as_uint(f);
    x += 0x7fffu + ((x >> 16) & 1u);
    return (u16)(x >> 16);
}
__device__ __forceinline__ u32 pack2(float a, float b) {
    return (u32)f2bf(a) | ((u32)f2bf(b) << 16);
}
__device__ __forceinline__ float sigm(float x) { return 1.0f / (1.0f + __expf(-x)); }
__device__ __forceinline__ float tanh_fast(float x) {
    float e2 = __expf(2.0f * x);
    return 1.0f - 2.0f / (e2 + 1.0f);   // safe at +inf
}
__device__ __forceinline__ void load_lds16(const void* g, void* l) {
    __builtin_amdgcn_global_load_lds(
        (const __attribute__((address_space(1))) u32*)g,
        (__attribute__((address_space(3))) u32*)l, 16, 0, 0);
}

// ---------------- kernel 0: transpose fp32 weights -> k-contiguous bf16 B layouts ----------------
__global__ __launch_bounds__(256) void k_prep_w(const float* __restrict__ eW,
                                                const float* __restrict__ aW,
                                                const float* __restrict__ sW,
                                                u16* __restrict__ Wt,
                                                u16* __restrict__ SWt) {
    int id = blockIdx.x * 256 + threadIdx.x;
    if (id < 131072) {
        int n = id >> 8, k = id & 255;
        Wt[n * 256 + k] = f2bf((n < 256) ? eW[k * 256 + n] : aW[k * 256 + (n - 256)]);
    } else {
        int id2 = id - 131072;
        if (id2 < 64 * 320) {
            int n = id2 / 320, k = id2 - n * 320;
            SWt[n * 320 + k] = (n < 50) ? f2bf(sW[k * 50 + n]) : (u16)0;
        }
    }
}

// ---------------- kernel 1: per-chunk-token softmax attention w [ctok][50] (bf16 out) ----------------
__global__ __launch_bounds__(256) void k_w(const int* __restrict__ q_data,
                                           const float* __restrict__ qeW,
                                           const float* __restrict__ Mk,
                                           u16* __restrict__ w_out,
                                           int t0, int tcl2) {
    __shared__ __align__(16) float mk[3200];       // Mk fp32 [50][64]
    __shared__ __align__(16) u16 wtile[256 * 50];
    int tid = threadIdx.x;
    for (int i = tid; i < 3200; i += 256) mk[i] = Mk[i];

    int ctok = blockIdx.x * 256 + tid;
    int b = ctok >> tcl2;
    int tc = ctok & ((1 << tcl2) - 1);
    int gtok = (b << 9) + t0 + tc;
    int q = q_data[gtok];

    float qe[64];
    {
        const float4* qr = (const float4*)(qeW + (size_t)q * 64);
#pragma unroll
        for (int i = 0; i < 16; i++) {
            float4 u = qr[i];
            qe[4 * i + 0] = u.x; qe[4 * i + 1] = u.y;
            qe[4 * i + 2] = u.z; qe[4 * i + 3] = u.w;
        }
    }
    __syncthreads();

    float lg[50];
#pragma unroll
    for (int m = 0; m < 50; m++) {
        const float* mr = &mk[m * 64];
        float acc = 0.f;
#pragma unroll
        for (int k = 0; k < 64; k++) acc = fmaf(qe[k], mr[k], acc);
        lg[m] = acc;
    }
    float mx = -1e30f;
#pragma unroll
    for (int m = 0; m < 50; m++) mx = fmaxf(mx, lg[m]);
    float sum = 0.f;
#pragma unroll
    for (int m = 0; m < 50; m++) { lg[m] = __expf(lg[m] - mx); sum += lg[m]; }
    float inv = 1.0f / sum;
#pragma unroll
    for (int m = 0; m < 50; m++) wtile[tid * 50 + m] = f2bf(lg[m] * inv);

    __syncthreads();

    int wave = tid >> 6, lane = tid & 63;
    int wave_ctok0 = blockIdx.x * 256 + wave * 64;
    const uint4* src = (const uint4*)(wtile + wave * 3200);
    uint4* dst = (uint4*)(w_out + (size_t)wave_ctok0 * 50);
    for (int c = lane; c < 400; c += 64) dst[c] = src[c];
}

// ---------------- kernel 1b: materialize ve [ctok][256] bf16 (thread = token x 8 cols) ----------------
__global__ __launch_bounds__(256) void k_ve(const int* __restrict__ q_data,
                                            const int* __restrict__ r_data,
                                            const float* __restrict__ vW,
                                            const float* __restrict__ vb,
                                            u16* __restrict__ ve,
                                            int t0, int tcl2) {
    int id = blockIdx.x * 256 + threadIdx.x;
    int ctok = id >> 5, seg = id & 31;
    int b = ctok >> tcl2;
    int tc = ctok & ((1 << tcl2) - 1);
    int gtok = (b << 9) + t0 + tc;
    int q = q_data[gtok];
    int idx = (q > 0) ? (q - 1) : 0;
    float rs = (float)r_data[gtok] * 0.25f;
    float vf = (q > 0) ? 1.0f : 0.0f;

    const float* pa = vW + (size_t)idx * 256 + seg * 8;
    const float* pb = pa + NQv * 256;
    float4 a0 = ((const float4*)pa)[0];
    float4 a1 = ((const float4*)pa)[1];
    float4 b0 = ((const float4*)pb)[0];
    float4 b1 = ((const float4*)pb)[1];
    const float* vbp = vb + seg * 8;
    float o0 = vf * fmaf(rs, b0.x, a0.x) + vbp[0];
    float o1 = vf * fmaf(rs, b0.y, a0.y) + vbp[1];
    float o2 = vf * fmaf(rs, b0.z, a0.z) + vbp[2];
    float o3 = vf * fmaf(rs, b0.w, a0.w) + vbp[3];
    float o4 = vf * fmaf(rs, b1.x, a1.x) + vbp[4];
    float o5 = vf * fmaf(rs, b1.y, a1.y) + vbp[5];
    float o6 = vf * fmaf(rs, b1.z, a1.z) + vbp[6];
    float o7 = vf * fmaf(rs, b1.w, a1.w) + vbp[7];
    uint4 o;
    o.x = pack2(o0, o1); o.y = pack2(o2, o3);
    o.z = pack2(o4, o5); o.w = pack2(o6, o7);
    *(uint4*)(ve + (size_t)ctok * 256 + seg * 8) = o;
}

// ---------------- kernel 2: erase/add MFMA GEMM, m97-style global_load_lds staging ----------------
__global__ __launch_bounds__(256) void k_gemm_ea(const u16* __restrict__ ve,
                                                 const u16* __restrict__ Wt,
                                                 const float* __restrict__ eb,
                                                 const float* __restrict__ ab,
                                                 u16* __restrict__ e_out,
                                                 u16* __restrict__ a_out) {
    __shared__ __align__(16) u16 smem[8192];   // lA[4096] | lB[4096]; reused as C-stage
    u16* lA = smem;
    u16* lB = smem + 4096;

    int tid = threadIdx.x;
    int row0 = blockIdx.x * 128;   // ctok space
    int col0 = blockIdx.y * 128;

    int wave = tid >> 6, lane = tid & 63;
    int wm = wave >> 1, wn = wave & 1;
    int rl = lane & 15, quad = lane >> 4;
    fx4 acc[4][4] = {};

    int c0 = tid, c1 = tid + 256;
    int r0_ = c0 >> 2, j0 = c0 & 3;
    int r1_ = c1 >> 2, j1 = c1 & 3;

    for (int k0 = 0; k0 < 256; k0 += 32) {
        load_lds16(ve + (size_t)(row0 + r0_) * 256 + k0 + j0 * 8, lA + c0 * 8);
        load_lds16(ve + (size_t)(row0 + r1_) * 256 + k0 + j1 * 8, lA + c1 * 8);
        load_lds16(Wt + (size_t)(col0 + r0_) * 256 + k0 + j0 * 8, lB + c0 * 8);
        load_lds16(Wt + (size_t)(col0 + r1_) * 256 + k0 + j1 * 8, lB + c1 * 8);
        __syncthreads();
        bf16x8 af[4], bfr[4];
#pragma unroll
        for (int i = 0; i < 4; i++) af[i] = *(const bf16x8*)(lA + (wm * 64 + i * 16 + rl) * 32 + quad * 8);
#pragma unroll
        for (int j = 0; j < 4; j++) bfr[j] = *(const bf16x8*)(lB + (wn * 64 + j * 16 + rl) * 32 + quad * 8);
#pragma unroll
        for (int i = 0; i < 4; i++)
#pragma unroll
            for (int j = 0; j < 4; j++)
                acc[i][j] = __builtin_amdgcn_mfma_f32_16x16x32_bf16(af[i], bfr[j], acc[i][j], 0, 0, 0);
        __syncthreads();
    }

    // coalesced epilogue via LDS C-stage (64 rows x 128 cols per half)
    bool is_er = (col0 < 256);
    const float* bias = is_er ? eb : ab;
    u16* outp = is_er ? e_out : a_out;
    int cb0 = col0 & 255;
    u16* cst = smem;   // 8192 u16
#pragma unroll
    for (int h = 0; h < 2; h++) {
        if (wm == h) {
#pragma unroll
            for (int j = 0; j < 4; j++) {
                int nl = wn * 64 + j * 16 + rl;
                float bv = bias[cb0 + nl];
#pragma unroll
                for (int i = 0; i < 4; i++) {
                    int rowl = i * 16 + quad * 4;
#pragma unroll
                    for (int r = 0; r < 4; r++) {
                        float x = acc[i][j][r] + bv;
                        cst[(rowl + r) * 128 + nl] = f2bf(is_er ? sigm(x) : tanh_fast(x));
                    }
                }
            }
        }
        __syncthreads();
#pragma unroll
        for (int c = 0; c < 4; c++) {
            int idx = c * 256 + tid;
            int row = idx >> 4, seg = idx & 15;
            *(uint4*)(outp + (size_t)(row0 + h * 64 + row) * 256 + cb0 + seg * 8) =
                *(const uint4*)(cst + row * 128 + seg * 8);
        }
        __syncthreads();
    }
}

// ---------------- kernel 3: scan, 8-step groups, double-buffered w, deep e/a prefetch ----------------
// e_buf and reads_out alias on purpose.
__global__ __launch_bounds__(256) void k_scan(const u16* __restrict__ w_buf,
                                              const u16* e_buf,
                                              const u16* __restrict__ a_buf,
                                              const float* __restrict__ Mv0,
                                              u16* __restrict__ Mv_state,
                                              u16* reads_out,
                                              int Tc, int first, int store) {
    int b = blockIdx.x;
    int tid = threadIdx.x;
    __shared__ float wls[2][8][52];

    float Mv[50];
    if (first) {
#pragma unroll
        for (int m = 0; m < 50; m++) Mv[m] = Mv0[m * 256 + tid];
    } else {
#pragma unroll
        for (int m = 0; m < 50; m++) Mv[m] = bf2f(Mv_state[((size_t)b * 50 + m) * 256 + tid]);
    }

    size_t base = (size_t)b * Tc;
    int ngrp = Tc >> 3;

    u16 eu[8], au[8];
#pragma unroll
    for (int s = 0; s < 8; s++) {
        eu[s] = e_buf[(base + s) * 256 + tid];
        au[s] = a_buf[(base + s) * 256 + tid];
    }
    if (tid < 200) {
        u32 w0 = ((const u32*)(w_buf + base * 50))[tid];
        int s = tid / 25, m = (tid % 25) * 2;
        wls[0][s][m] = bflo(w0);
        wls[0][s][m + 1] = bfhi(w0);
    }
    __syncthreads();

    for (int g = 0; g < ngrp; g++) {
        int cur = g & 1, nxt = cur ^ 1;
        bool has_next = (g + 1 < ngrp);
        size_t nbase = base + (size_t)(g + 1) * 8;

        u16 eun[8], aun[8];
        u32 wn_ = 0;
        if (has_next) {
#pragma unroll
            for (int s = 0; s < 8; s++) {
                eun[s] = e_buf[(nbase + s) * 256 + tid];
                aun[s] = a_buf[(nbase + s) * 256 + tid];
            }
            if (tid < 200) wn_ = ((const u32*)(w_buf + nbase * 50))[tid];
        }

#pragma unroll
        for (int s = 0; s < 8; s++) {
            float e = bf2f(eu[s]), a = bf2f(au[s]);
            const float* wv = wls[cur][s];
            float rd = 0.f;
#pragma unroll
            for (int m = 0; m < 50; m++) {
                float wm = wv[m];
                rd = fmaf(wm, Mv[m], rd);                 // read BEFORE write
                float tmp = fmaf(-e, Mv[m], a);           // a - e*Mv
                Mv[m] = fmaf(wm, tmp, Mv[m]);             // Mv + w*(a - e*Mv)
            }
            reads_out[(base + g * 8 + s) * 256 + tid] = f2bf(rd);
        }

        if (has_next) {
            if (tid < 200) {
                int s = tid / 25, m = (tid % 25) * 2;
                wls[nxt][s][m] = bflo(wn_);
                wls[nxt][s][m + 1] = bfhi(wn_);
            }
#pragma unroll
            for (int s = 0; s < 8; s++) { eu[s] = eun[s]; au[s] = aun[s]; }
        }
        __syncthreads();
    }

    if (store) {
#pragma unroll
        for (int m = 0; m < 50; m++) Mv_state[((size_t)b * 50 + m) * 256 + tid] = f2bf(Mv[m]);
    }
}

// ---------------- kernel 4: fused summary MFMA + heads (fp32 out), padded LDS ----------------
__global__ __launch_bounds__(256) void k_sum_heads(const u16* __restrict__ reads,
                                                   const int* __restrict__ q_data,
                                                   const float* __restrict__ qeW,
                                                   const u16* __restrict__ SWt,
                                                   const float* __restrict__ sb,
                                                   const float* __restrict__ abilW,
                                                   const float* __restrict__ abilb,
                                                   const float* __restrict__ tW,
                                                   const float* __restrict__ tb,
                                                   const float* __restrict__ dW,
                                                   const float* __restrict__ db,
                                                   const float* __restrict__ cW,
                                                   const float* __restrict__ cb,
                                                   float* __restrict__ out,
                                                   int t0, int tcl2) {
    __shared__ __align__(16) u16 lA[128 * LP];
    __shared__ __align__(16) u16 lB[64 * LP];
    __shared__ float sS[128 * 52];
    __shared__ int s_q[128];
    int tid = threadIdx.x;
    int row0 = blockIdx.x * 128;
    if (tid < 128) {
        int ctok = row0 + tid;
        int b = ctok >> tcl2;
        int tc = ctok & ((1 << tcl2) - 1);
        s_q[tid] = q_data[(b << 9) + t0 + tc];
    }
    int wave = tid >> 6, lane = tid & 63;
    int wm = wave >> 1, wn = wave & 1;
    int rl = lane & 15, quad = lane >> 4;
    fx4 acc[4][2] = {};
    __syncthreads();

    for (int ks = 0; ks < 10; ks++) {
        int k0 = ks * 32;
#pragma unroll
        for (int h = 0; h < 2; h++) {
            int c = tid + h * 256;
            int row = c >> 2, j = c & 3;
            if (k0 < 256) {
                uint4 u = *(const uint4*)(reads + (size_t)(row0 + row) * 256 + k0 + j * 8);
                *(uint4*)(lA + row * LP + j * 8) = u;
            } else {
                const float* src = qeW + (size_t)s_q[row] * 64 + (k0 - 256) + j * 8;
                float4 f0 = ((const float4*)src)[0];
                float4 f1 = ((const float4*)src)[1];
                uint4 o;
                o.x = pack2(f0.x, f0.y); o.y = pack2(f0.z, f0.w);
                o.z = pack2(f1.x, f1.y); o.w = pack2(f1.z, f1.w);
                *(uint4*)(lA + row * LP + j * 8) = o;
            }
        }
        {
            int n = tid >> 2, j = tid & 3;
            uint4 u = *(const uint4*)(SWt + (size_t)n * 320 + k0 + j * 8);
            *(uint4*)(lB + n * LP + j * 8) = u;
        }
        __syncthreads();
        bf16x8 af[4], bfr[2];
#pragma unroll
        for (int i = 0; i < 4; i++) af[i] = *(const bf16x8*)(lA + (wm * 64 + i * 16 + rl) * LP + quad * 8);
#pragma unroll
        for (int j = 0; j < 2; j++) bfr[j] = *(const bf16x8*)(lB + (wn * 32 + j * 16 + rl) * LP + quad * 8);
#pragma unroll
        for (int i = 0; i < 4; i++)
#pragma unroll
            for (int j = 0; j < 2; j++)
                acc[i][j] = __builtin_amdgcn_mfma_f32_16x16x32_bf16(af[i], bfr[j], acc[i][j], 0, 0, 0);
        __syncthreads();
    }

#pragma unroll
    for (int j = 0; j < 2; j++) {
        int n = wn * 32 + j * 16 + rl;
        if (n < 50) {
            float bv = sb[n];
#pragma unroll
            for (int i = 0; i < 4; i++) {
                int rowl = wm * 64 + i * 16 + quad * 4;
#pragma unroll
                for (int r = 0; r < 4; r++)
                    sS[(rowl + r) * 52 + n] = tanh_fast(acc[i][j][r] + bv);
            }
        }
    }
    __syncthreads();

    if (tid < 128) {
        int ctok = row0 + tid;
        int b = ctok >> tcl2;
        int tc = ctok & ((1 << tcl2) - 1);
        int gtok = (b << 9) + t0 + tc;
        const float* sp = &sS[tid * 52];

        float qe[64];
        const float4* qr = (const float4*)(qeW + (size_t)s_q[tid] * 64);
#pragma unroll
        for (int i = 0; i < 16; i++) {
            float4 u = qr[i];
            qe[4 * i + 0] = u.x; qe[4 * i + 1] = u.y;
            qe[4 * i + 2] = u.z; qe[4 * i + 3] = u.w;
        }
        float th = abilb[0];
#pragma unroll
        for (int j = 0; j < 50; j++) th = fmaf(sp[j], abilW[j], th);
        out[gtok] = th * 3.0f;

        float bt0 = tb[0], bt1 = tb[1], bt2 = tb[2], bt3 = tb[3];
#pragma unroll
        for (int k = 0; k < 64; k++) {
            float x = qe[k];
            bt0 = fmaf(x, tW[k * 4 + 0], bt0);
            bt1 = fmaf(x, tW[k * 4 + 1], bt1);
            bt2 = fmaf(x, tW[k * 4 + 2], bt2);
            bt3 = fmaf(x, tW[k * 4 + 3], bt3);
        }
        out[NT + (size_t)gtok * 4 + 0] = bt0;
        out[NT + (size_t)gtok * 4 + 1] = bt1;
        out[NT + (size_t)gtok * 4 + 2] = bt2;
        out[NT + (size_t)gtok * 4 + 3] = bt3;

        float da = db[0];
        float l0 = cb[0], l1 = cb[1], l2 = cb[2], l3 = cb[3];
#pragma unroll
        for (int i = 0; i < 50; i++) {
            float x = sp[i];
            da = fmaf(x, dW[i], da);
            l0 = fmaf(x, cW[i * 4 + 0], l0);
            l1 = fmaf(x, cW[i * 4 + 1], l1);
            l2 = fmaf(x, cW[i * 4 + 2], l2);
            l3 = fmaf(x, cW[i * 4 + 3], l3);
        }
#pragma unroll
        for (int k = 0; k < 64; k++) {
            float x = qe[k];
            int i = 50 + k;
            da = fmaf(x, dW[i], da);
            l0 = fmaf(x, cW[i * 4 + 0], l0);
            l1 = fmaf(x, cW[i * 4 + 1], l1);
            l2 = fmaf(x, cW[i * 4 + 2], l2);
            l3 = fmaf(x, cW[i * 4 + 3], l3);
        }
        float alpha = logf(1.0f + __expf(da));
        out[5 * (size_t)NT + gtok] = alpha;

        out[11 * (size_t)NT + (size_t)gtok * 4 + 0] = l0;
        out[11 * (size_t)NT + (size_t)gtok * 4 + 1] = l1;
        out[11 * (size_t)NT + (size_t)gtok * 4 + 2] = l2;
        out[11 * (size_t)NT + (size_t)gtok * 4 + 3] = l3;

        float c0 = sigm(l0);
        float c1 = c0 * sigm(l1);
        float c2 = c1 * sigm(l2);
        float c3 = c2 * sigm(l3);
        size_t pb = 6 * (size_t)NT + (size_t)gtok * 5;
        out[pb + 0] = 1.0f - c0;
        out[pb + 1] = c0 - c1;
        out[pb + 2] = c1 - c2;
        out[pb + 3] = c2 - c3;
        out[pb + 4] = c3;
    }
}

extern "C" void kernel_launch(void* const* d_in, const int* in_sizes, int n_in,
                              void* d_out, int out_size, void* d_ws, size_t ws_size,
                              hipStream_t stream) {
    (void)in_sizes; (void)n_in; (void)out_size;
    const int* q_data = (const int*)d_in[0];
    const int* r_data = (const int*)d_in[1];
    const float* qeW = (const float*)d_in[2];
    const float* Mk  = (const float*)d_in[3];
    const float* Mv0 = (const float*)d_in[4];
    const float* vW  = (const float*)d_in[5];
    const float* vb  = (const float*)d_in[6];
    const float* eW  = (const float*)d_in[7];
    const float* eb  = (const float*)d_in[8];
    const float* aW  = (const float*)d_in[9];
    const float* ab  = (const float*)d_in[10];
    const float* sW  = (const float*)d_in[11];
    const float* sb  = (const float*)d_in[12];
    const float* abilW = (const float*)d_in[13];
    const float* abilb = (const float*)d_in[14];
    const float* tW  = (const float*)d_in[15];
    const float* tb  = (const float*)d_in[16];
    const float* dW  = (const float*)d_in[17];
    const float* db  = (const float*)d_in[18];
    const float* cW  = (const float*)d_in[19];
    const float* cb  = (const float*)d_in[20];

    // bf16 workspace. footprint(Tc) = 13,410,304 + 837,632*Tc bytes (ws ~268 MB observed)
    int Tc = 8;
    const int cands[6] = {256, 128, 64, 32, 16, 8};
    for (int i = 0; i < 6; i++) {
        size_t need = 13410304ULL + 837632ULL * (size_t)cands[i];
        if (need <= ws_size) { Tc = cands[i]; break; }
    }
    int tcl2 = 31 - __builtin_clz((u32)Tc);
    int nch = T_LEN / Tc;

    char* ws = (char*)d_ws;
    u16* Wt    = (u16*)(ws + 0);                          // 262,144 B
    u16* SWt   = (u16*)(ws + 262144);                     // 40,960 B
    u16* MvSt  = (u16*)(ws + 303104);                     // 13,107,200 B (bf16 state)
    u16* w_c   = (u16*)(ws + 13410304);                   // 51,200*Tc B
    u16* ve_c  = (u16*)(ws + 13410304 + 51200ULL * Tc);   // 262,144*Tc B
    u16* e_c   = (u16*)(ws + 13410304 + 313344ULL * Tc);  // 262,144*Tc B (alias reads)
    u16* a_c   = (u16*)(ws + 13410304 + 575488ULL * Tc);  // 262,144*Tc B
    u16* reads = e_c;
    float* out = (float*)d_out;

    int rows = B_SZ * Tc;

    k_prep_w<<<592, 256, 0, stream>>>(eW, aW, sW, Wt, SWt);
    for (int c = 0; c < nch; c++) {
        int t0 = c * Tc;
        k_w<<<rows / 256, 256, 0, stream>>>(q_data, qeW, Mk, w_c, t0, tcl2);
        k_ve<<<rows / 8, 256, 0, stream>>>(q_data, r_data, vW, vb, ve_c, t0, tcl2);
        dim3 g2(rows / 128, 4);
        k_gemm_ea<<<g2, 256, 0, stream>>>(ve_c, Wt, eb, ab, e_c, a_c);
        k_scan<<<B_SZ, 256, 0, stream>>>(w_c, e_c, a_c, Mv0, MvSt, reads, Tc,
                                         (c == 0) ? 1 : 0, (c < nch - 1) ? 1 : 0);
        k_sum_heads<<<rows / 128, 256, 0, stream>>>(reads, q_data, qeW, SWt, sb,
                                                    abilW, abilb, tW, tb, dW, db, cW, cb,
                                                    out, t0, tcl2);
    }
}